// Round 1
// baseline (1400.205 us; speedup 1.0000x reference)
//
#include <hip/hip_runtime.h>

#define NN 100000   // nodes
#define FE 128      // node features
#define HD 128      // hidden
#define EE 1600000  // edges
#define BQ 65536    // queries
#define TDm 64      // temporal dim

// ---------------- degree / sort-by-dst machinery ----------------

__global__ __launch_bounds__(256) void k_hist(const int* __restrict__ dst,
                                              int* __restrict__ counts) {
    int i = blockIdx.x * 256 + threadIdx.x;
    if (i < EE) atomicAdd(&counts[dst[i]], 1);
}

__global__ __launch_bounds__(256) void k_dinv(const int* __restrict__ counts,
                                              float* __restrict__ dinv) {
    int i = blockIdx.x * 256 + threadIdx.x;
    if (i < NN) dinv[i] = rsqrtf((float)counts[i] + 1.0f);
}

// block sums of 1024-element chunks
__global__ __launch_bounds__(256) void k_scan1(const int* __restrict__ counts,
                                               int* __restrict__ bsum) {
    __shared__ int sd[256];
    int t = threadIdx.x, b = blockIdx.x;
    int s = 0;
#pragma unroll
    for (int j = 0; j < 4; j++) {
        int i = b * 1024 + t + 256 * j;
        if (i < NN) s += counts[i];
    }
    sd[t] = s;
    __syncthreads();
    for (int o = 128; o > 0; o >>= 1) {
        if (t < o) sd[t] += sd[t + o];
        __syncthreads();
    }
    if (t == 0) bsum[b] = sd[0];
}

__global__ void k_scan2(int* bsum, int nch) {
    if (threadIdx.x == 0 && blockIdx.x == 0) {
        int run = 0;
        for (int i = 0; i < nch; i++) { int v = bsum[i]; bsum[i] = run; run += v; }
    }
}

__global__ __launch_bounds__(256) void k_scan3(const int* __restrict__ counts,
                                               const int* __restrict__ bsum,
                                               int* __restrict__ offsets) {
    __shared__ int sd[256];
    int t = threadIdx.x, b = blockIdx.x;
    int base = b * 1024 + 4 * t;
    int v0 = (base + 0 < NN) ? counts[base + 0] : 0;
    int v1 = (base + 1 < NN) ? counts[base + 1] : 0;
    int v2 = (base + 2 < NN) ? counts[base + 2] : 0;
    int v3 = (base + 3 < NN) ? counts[base + 3] : 0;
    int p1 = v0, p2 = p1 + v1, p3 = p2 + v2, ts = p3 + v3;
    sd[t] = ts;
    __syncthreads();
    for (int o = 1; o < 256; o <<= 1) {
        int x = (t >= o) ? sd[t - o] : 0;
        __syncthreads();
        sd[t] += x;
        __syncthreads();
    }
    int excl = sd[t] - ts + bsum[b];
    if (base + 0 < NN) offsets[base + 0] = excl;
    if (base + 1 < NN) offsets[base + 1] = excl + p1;
    if (base + 2 < NN) offsets[base + 2] = excl + p2;
    if (base + 3 < NN) offsets[base + 3] = excl + p3;
    if (b == 0 && t == 0) offsets[NN] = EE;
}

__global__ __launch_bounds__(256) void k_scatter(const int* __restrict__ src,
                                                 const int* __restrict__ dst,
                                                 const int* __restrict__ offsets,
                                                 int* __restrict__ cursor,
                                                 const float* __restrict__ dinv,
                                                 int* __restrict__ ssrc,
                                                 float* __restrict__ scoef) {
    int e = blockIdx.x * 256 + threadIdx.x;
    if (e >= EE) return;
    int d = dst[e], s = src[e];
    int p = offsets[d] + atomicAdd(&cursor[d], 1);
    ssrc[p] = s;
    scoef[p] = dinv[s] * dinv[d];
}

// ---------------- fp32 tiled GEMM: C[M,NC] = A[M,K] @ W[K,NC] (+bias)(+relu) --------
// block = 256 threads, 64 rows x NC cols per block; thread = RPT rows x 4 cols.

template <int K, int NC, int ACT>  // ACT: 0=none, 1=relu
__global__ __launch_bounds__(256) void k_gemm(const float* __restrict__ A,
                                              const float* __restrict__ W,
                                              const float* __restrict__ bias,
                                              float* __restrict__ C, int M) {
    constexpr int G = NC / 4;    // col groups
    constexpr int RG = 256 / G;  // row groups
    constexpr int RPT = 64 / RG; // rows per thread
    __shared__ float Wl[64 * NC];
    __shared__ float Al[64 * 64];
    const int t = threadIdx.x;
    const int cg = t % G, rg = t / G;
    const int row0 = blockIdx.x * 64;
    float acc[RPT][4];
#pragma unroll
    for (int i = 0; i < RPT; i++) { acc[i][0] = acc[i][1] = acc[i][2] = acc[i][3] = 0.f; }

    for (int k0 = 0; k0 < K; k0 += 64) {
#pragma unroll
        for (int it = 0; it < NC / 16; it++) {          // stage W tile 64 x NC
            int idx = it * 256 + t;
            int kk = idx / (NC / 4);
            int c4 = idx % (NC / 4);
            *(float4*)&Wl[kk * NC + 4 * c4] =
                *(const float4*)&W[(size_t)(k0 + kk) * NC + 4 * c4];
        }
#pragma unroll
        for (int it = 0; it < 4; it++) {                // stage A tile 64 x 64
            int idx = it * 256 + t;
            int r = idx / 16, q = idx % 16;
            int grow = row0 + r;
            float4 v = make_float4(0.f, 0.f, 0.f, 0.f);
            if (grow < M) v = *(const float4*)&A[(size_t)grow * K + k0 + 4 * q];
            *(float4*)&Al[r * 64 + 4 * q] = v;
        }
        __syncthreads();
#pragma unroll 4
        for (int kk = 0; kk < 64; kk += 4) {
            float4 w0 = *(float4*)&Wl[(kk + 0) * NC + 4 * cg];
            float4 w1 = *(float4*)&Wl[(kk + 1) * NC + 4 * cg];
            float4 w2 = *(float4*)&Wl[(kk + 2) * NC + 4 * cg];
            float4 w3 = *(float4*)&Wl[(kk + 3) * NC + 4 * cg];
#pragma unroll
            for (int i = 0; i < RPT; i++) {
                float4 a = *(float4*)&Al[(rg * RPT + i) * 64 + kk];
                acc[i][0] = fmaf(a.x, w0.x, fmaf(a.y, w1.x, fmaf(a.z, w2.x, fmaf(a.w, w3.x, acc[i][0]))));
                acc[i][1] = fmaf(a.x, w0.y, fmaf(a.y, w1.y, fmaf(a.z, w2.y, fmaf(a.w, w3.y, acc[i][1]))));
                acc[i][2] = fmaf(a.x, w0.z, fmaf(a.y, w1.z, fmaf(a.z, w2.z, fmaf(a.w, w3.z, acc[i][2]))));
                acc[i][3] = fmaf(a.x, w0.w, fmaf(a.y, w1.w, fmaf(a.z, w2.w, fmaf(a.w, w3.w, acc[i][3]))));
            }
        }
        __syncthreads();
    }
    float4 bv = make_float4(0.f, 0.f, 0.f, 0.f);
    if (bias) bv = *(const float4*)&bias[4 * cg];
#pragma unroll
    for (int i = 0; i < RPT; i++) {
        int r = row0 + rg * RPT + i;
        if (r < M) {
            float4 o;
            o.x = acc[i][0] + bv.x; o.y = acc[i][1] + bv.y;
            o.z = acc[i][2] + bv.z; o.w = acc[i][3] + bv.w;
            if (ACT == 1) {
                o.x = fmaxf(o.x, 0.f); o.y = fmaxf(o.y, 0.f);
                o.z = fmaxf(o.z, 0.f); o.w = fmaxf(o.w, 0.f);
            }
            *(float4*)&C[(size_t)r * NC + 4 * cg] = o;
        }
    }
}

// ---------------- edge aggregation: out = relu(sum_in + self + bias) ----------------
// one wave per node; lane holds float2 of the 128-wide feature row.

__global__ __launch_bounds__(256) void k_agg(const float* __restrict__ hw,
                                             const int* __restrict__ ssrc,
                                             const float* __restrict__ scoef,
                                             const int* __restrict__ offsets,
                                             const float* __restrict__ dinv,
                                             const float* __restrict__ bias,
                                             float* __restrict__ out) {
    int node = blockIdx.x * 4 + (threadIdx.x >> 6);
    int lane = threadIdx.x & 63;
    if (node >= NN) return;
    const float2* hw2 = (const float2*)hw;
    float di = dinv[node];
    float2 hs = hw2[(size_t)node * 64 + lane];
    float ax = hs.x * di * di, ay = hs.y * di * di;
    int beg = offsets[node], end = offsets[node + 1];
    for (int e = beg; e < end; e++) {
        int s = ssrc[e];
        float c = scoef[e];
        float2 v = hw2[(size_t)s * 64 + lane];
        ax = fmaf(v.x, c, ax);
        ay = fmaf(v.y, c, ay);
    }
    float2 bb = ((const float2*)bias)[lane];
    ax = fmaxf(ax + bb.x, 0.f);
    ay = fmaxf(ay + bb.y, 0.f);
    float2 o; o.x = ax; o.y = ay;
    ((float2*)out)[(size_t)node * 64 + lane] = o;
}

// ---------------- temporal-input gather: tin[r] = [day_tab[day[r]] ; time_tab[time[r]]]

__global__ __launch_bounds__(256) void k_tin(const int* __restrict__ day_ids,
                                             const int* __restrict__ time_ids,
                                             const float* __restrict__ day_table,
                                             const float* __restrict__ time_table,
                                             float* __restrict__ tin) {
    int idx = blockIdx.x * 256 + threadIdx.x;  // float4 index
    int r = idx / 32, q = idx % 32;
    if (r >= BQ) return;
    float4 v;
    if (q < 16) v = *(const float4*)&day_table[(size_t)day_ids[r] * 64 + 4 * q];
    else        v = *(const float4*)&time_table[(size_t)time_ids[r] * 64 + 4 * (q - 16)];
    ((float4*)tin)[idx] = v;
}

// ---------------- head layer 1: fused gather-GEMM, K=448 -> NC=256, relu ------------

__global__ __launch_bounds__(256) void k_head1(const float* __restrict__ h,
                                               const float* __restrict__ temporal,
                                               const int* __restrict__ orig,
                                               const int* __restrict__ destid,
                                               const int* __restrict__ mode_ids,
                                               const float* __restrict__ mode_table,
                                               const float* __restrict__ W,
                                               const float* __restrict__ bias,
                                               float* __restrict__ z1) {
    __shared__ float Wl[64 * 256];
    __shared__ float Al[64 * 64];
    const int t = threadIdx.x;
    const int cg = t & 63, rg = t >> 6;  // G=64, RG=4, RPT=16
    const int row0 = blockIdx.x * 64;
    float acc[16][4];
#pragma unroll
    for (int i = 0; i < 16; i++) { acc[i][0] = acc[i][1] = acc[i][2] = acc[i][3] = 0.f; }

    for (int k0 = 0; k0 < 448; k0 += 64) {
#pragma unroll
        for (int it = 0; it < 16; it++) {  // stage W tile 64x256
            int idx = it * 256 + t;
            int kk = idx >> 6, c4 = idx & 63;
            *(float4*)&Wl[kk * 256 + 4 * c4] =
                *(const float4*)&W[(size_t)(k0 + kk) * 256 + 4 * c4];
        }
#pragma unroll
        for (int it = 0; it < 4; it++) {   // stage gathered A tile 64x64
            int idx = it * 256 + t;
            int r = idx >> 4, q = idx & 15;
            int grow = row0 + r;
            int gk = k0 + 4 * q;
            float4 v;
            if (gk < 128)      v = *(const float4*)&h[(size_t)orig[grow] * 128 + gk];
            else if (gk < 256) v = *(const float4*)&h[(size_t)destid[grow] * 128 + (gk - 128)];
            else if (gk < 384) v = *(const float4*)&temporal[(size_t)grow * 128 + (gk - 256)];
            else               v = *(const float4*)&mode_table[(size_t)mode_ids[grow] * 64 + (gk - 384)];
            *(float4*)&Al[r * 64 + 4 * q] = v;
        }
        __syncthreads();
#pragma unroll 4
        for (int kk = 0; kk < 64; kk += 4) {
            float4 w0 = *(float4*)&Wl[(kk + 0) * 256 + 4 * cg];
            float4 w1 = *(float4*)&Wl[(kk + 1) * 256 + 4 * cg];
            float4 w2 = *(float4*)&Wl[(kk + 2) * 256 + 4 * cg];
            float4 w3 = *(float4*)&Wl[(kk + 3) * 256 + 4 * cg];
#pragma unroll
            for (int i = 0; i < 16; i++) {
                float4 a = *(float4*)&Al[(rg * 16 + i) * 64 + kk];
                acc[i][0] = fmaf(a.x, w0.x, fmaf(a.y, w1.x, fmaf(a.z, w2.x, fmaf(a.w, w3.x, acc[i][0]))));
                acc[i][1] = fmaf(a.x, w0.y, fmaf(a.y, w1.y, fmaf(a.z, w2.y, fmaf(a.w, w3.y, acc[i][1]))));
                acc[i][2] = fmaf(a.x, w0.z, fmaf(a.y, w1.z, fmaf(a.z, w2.z, fmaf(a.w, w3.z, acc[i][2]))));
                acc[i][3] = fmaf(a.x, w0.w, fmaf(a.y, w1.w, fmaf(a.z, w2.w, fmaf(a.w, w3.w, acc[i][3]))));
            }
        }
        __syncthreads();
    }
    float4 bv = *(const float4*)&bias[4 * cg];
#pragma unroll
    for (int i = 0; i < 16; i++) {
        int r = row0 + rg * 16 + i;
        float4 o;
        o.x = fmaxf(acc[i][0] + bv.x, 0.f);
        o.y = fmaxf(acc[i][1] + bv.y, 0.f);
        o.z = fmaxf(acc[i][2] + bv.z, 0.f);
        o.w = fmaxf(acc[i][3] + bv.w, 0.f);
        *(float4*)&z1[(size_t)r * 256 + 4 * cg] = o;
    }
}

// ---------------- head layer 4: [B,64] @ [64,1] + sigmoid ---------------------------

__global__ __launch_bounds__(256) void k_head4(const float* __restrict__ z3,
                                               const float* __restrict__ Wh4,
                                               const float* __restrict__ bh4,
                                               float* __restrict__ out) {
    __shared__ float w[64];
    int t = threadIdx.x;
    if (t < 64) w[t] = Wh4[t];
    __syncthreads();
    int r = blockIdx.x * 16 + (t / 16);
    int q = t % 16;
    const float4* z4 = (const float4*)z3;
    float4 v = z4[(size_t)r * 16 + q];
    float4 wq = *(const float4*)&w[4 * q];
    float s = v.x * wq.x + v.y * wq.y + v.z * wq.z + v.w * wq.w;
#pragma unroll
    for (int off = 1; off < 16; off <<= 1) s += __shfl_xor(s, off, 64);
    if (q == 0) out[r] = 1.0f / (1.0f + expf(-(s + bh4[0])));
}

// ---------------- launch ------------------------------------------------------------

extern "C" void kernel_launch(void* const* d_in, const int* in_sizes, int n_in,
                              void* d_out, int out_size, void* d_ws, size_t ws_size,
                              hipStream_t stream) {
    const float* x          = (const float*)d_in[0];
    const int*   eidx       = (const int*)d_in[1];
    const int*   esrc       = eidx;
    const int*   edst       = eidx + EE;
    const int*   origin     = (const int*)d_in[2];
    const int*   destid     = (const int*)d_in[3];
    const int*   day_ids    = (const int*)d_in[4];
    const int*   time_ids   = (const int*)d_in[5];
    const int*   mode_ids   = (const int*)d_in[6];
    const float* W1 = (const float*)d_in[7];   const float* b1 = (const float*)d_in[8];
    const float* W2 = (const float*)d_in[9];   const float* b2 = (const float*)d_in[10];
    const float* W3 = (const float*)d_in[11];  const float* b3 = (const float*)d_in[12];
    const float* day_table  = (const float*)d_in[13];
    const float* time_table = (const float*)d_in[14];
    const float* mode_table = (const float*)d_in[15];
    const float* Wf  = (const float*)d_in[16]; const float* bf  = (const float*)d_in[17];
    const float* Wh1 = (const float*)d_in[18]; const float* bh1 = (const float*)d_in[19];
    const float* Wh2 = (const float*)d_in[20]; const float* bh2 = (const float*)d_in[21];
    const float* Wh3 = (const float*)d_in[22]; const float* bh3 = (const float*)d_in[23];
    const float* Wh4 = (const float*)d_in[24]; const float* bh4 = (const float*)d_in[25];
    float* out = (float*)d_out;

    char* wsb = (char*)d_ws;
    size_t off = 0;
    auto alloc = [&](size_t bytes) -> char* {
        char* p = wsb + off;
        off = (off + bytes + 511) & ~(size_t)511;
        return p;
    };
    int*   counts  = (int*)alloc((size_t)NN * 4);
    int*   cursor  = (int*)alloc((size_t)NN * 4);
    int*   offsets = (int*)alloc((size_t)(NN + 1) * 4);
    int*   bsum    = (int*)alloc(128 * 4);
    float* dinv    = (float*)alloc((size_t)NN * 4);
    int*   ssrc    = (int*)alloc((size_t)EE * 4);
    float* scoef   = (float*)alloc((size_t)EE * 4);
    float* bufA    = (float*)alloc((size_t)NN * 128 * 4);
    float* bufB    = (float*)alloc((size_t)NN * 128 * 4);
    float* z1      = (float*)alloc((size_t)BQ * 256 * 4);
    // reuse: after GCN finishes, bufA is free
    float* tin      = z1;                       // dead before z1 is produced
    float* temporal = bufA;                     // [B,128], alive through head1
    float* z2       = bufA;                     // overwrites temporal after head1
    float* z3       = bufA + (size_t)BQ * 128;  // disjoint from z2

    hipMemsetAsync(counts, 0, (size_t)NN * 4, stream);
    hipMemsetAsync(cursor, 0, (size_t)NN * 4, stream);
    k_hist<<<(EE + 255) / 256, 256, 0, stream>>>(edst, counts);
    k_dinv<<<(NN + 255) / 256, 256, 0, stream>>>(counts, dinv);
    const int NCH = (NN + 1023) / 1024;  // 98
    k_scan1<<<NCH, 256, 0, stream>>>(counts, bsum);
    k_scan2<<<1, 64, 0, stream>>>(bsum, NCH);
    k_scan3<<<NCH, 256, 0, stream>>>(counts, bsum, offsets);
    k_scatter<<<(EE + 255) / 256, 256, 0, stream>>>(esrc, edst, offsets, cursor, dinv, ssrc, scoef);

    const int GB = (NN + 63) / 64;  // 1563
    k_gemm<128, 128, 0><<<GB, 256, 0, stream>>>(x, W1, nullptr, bufA, NN);
    k_agg<<<(NN + 3) / 4, 256, 0, stream>>>(bufA, ssrc, scoef, offsets, dinv, b1, bufB);
    k_gemm<128, 128, 0><<<GB, 256, 0, stream>>>(bufB, W2, nullptr, bufA, NN);
    k_agg<<<(NN + 3) / 4, 256, 0, stream>>>(bufA, ssrc, scoef, offsets, dinv, b2, bufB);
    k_gemm<128, 128, 0><<<GB, 256, 0, stream>>>(bufB, W3, nullptr, bufA, NN);
    k_agg<<<(NN + 3) / 4, 256, 0, stream>>>(bufA, ssrc, scoef, offsets, dinv, b3, bufB);
    // h_final = bufB

    k_tin<<<(BQ * 32) / 256, 256, 0, stream>>>(day_ids, time_ids, day_table, time_table, tin);
    k_gemm<128, 128, 1><<<BQ / 64, 256, 0, stream>>>(tin, Wf, bf, temporal, BQ);
    k_head1<<<BQ / 64, 256, 0, stream>>>(bufB, temporal, origin, destid, mode_ids, mode_table,
                                         Wh1, bh1, z1);
    k_gemm<256, 128, 1><<<BQ / 64, 256, 0, stream>>>(z1, Wh2, bh2, z2, BQ);
    k_gemm<128, 64, 1><<<BQ / 64, 256, 0, stream>>>(z2, Wh3, bh3, z3, BQ);
    k_head4<<<BQ / 16, 256, 0, stream>>>(z3, Wh4, bh4, out);
}

// Round 2
// 990.891 us; speedup vs baseline: 1.4131x; 1.4131x over previous
//
#include <hip/hip_runtime.h>

#define NN 100000   // nodes
#define EE 1600000  // edges
#define BQ 65536    // queries

typedef __attribute__((ext_vector_type(8))) short short8;
typedef __attribute__((ext_vector_type(4))) float f32x4;

__device__ __forceinline__ unsigned short bf16_rn(float f) {
    unsigned u = __builtin_bit_cast(unsigned, f);
    u += 0x7fff + ((u >> 16) & 1);
    return (unsigned short)(u >> 16);
}
__device__ __forceinline__ float bf2f(unsigned short h) {
    unsigned u = ((unsigned)h) << 16;
    return __builtin_bit_cast(float, u);
}

// ---------------- degree / sort-by-dst machinery ----------------

__global__ __launch_bounds__(256) void k_hist(const int* __restrict__ dst,
                                              int* __restrict__ counts) {
    int i = blockIdx.x * 256 + threadIdx.x;
    if (i < EE) atomicAdd(&counts[dst[i]], 1);
}

__global__ __launch_bounds__(256) void k_dinv(const int* __restrict__ counts,
                                              float* __restrict__ dinv) {
    int i = blockIdx.x * 256 + threadIdx.x;
    if (i < NN) dinv[i] = rsqrtf((float)counts[i] + 1.0f);
}

__global__ __launch_bounds__(256) void k_scan1(const int* __restrict__ counts,
                                               int* __restrict__ bsum) {
    __shared__ int sd[256];
    int t = threadIdx.x, b = blockIdx.x;
    int s = 0;
#pragma unroll
    for (int j = 0; j < 4; j++) {
        int i = b * 1024 + t + 256 * j;
        if (i < NN) s += counts[i];
    }
    sd[t] = s;
    __syncthreads();
    for (int o = 128; o > 0; o >>= 1) {
        if (t < o) sd[t] += sd[t + o];
        __syncthreads();
    }
    if (t == 0) bsum[b] = sd[0];
}

__global__ void k_scan2(int* bsum, int nch) {
    if (threadIdx.x == 0 && blockIdx.x == 0) {
        int run = 0;
        for (int i = 0; i < nch; i++) { int v = bsum[i]; bsum[i] = run; run += v; }
    }
}

__global__ __launch_bounds__(256) void k_scan3(const int* __restrict__ counts,
                                               const int* __restrict__ bsum,
                                               int* __restrict__ offsets) {
    __shared__ int sd[256];
    int t = threadIdx.x, b = blockIdx.x;
    int base = b * 1024 + 4 * t;
    int v0 = (base + 0 < NN) ? counts[base + 0] : 0;
    int v1 = (base + 1 < NN) ? counts[base + 1] : 0;
    int v2 = (base + 2 < NN) ? counts[base + 2] : 0;
    int v3 = (base + 3 < NN) ? counts[base + 3] : 0;
    int p1 = v0, p2 = p1 + v1, p3 = p2 + v2, ts = p3 + v3;
    sd[t] = ts;
    __syncthreads();
    for (int o = 1; o < 256; o <<= 1) {
        int x = (t >= o) ? sd[t - o] : 0;
        __syncthreads();
        sd[t] += x;
        __syncthreads();
    }
    int excl = sd[t] - ts + bsum[b];
    if (base + 0 < NN) offsets[base + 0] = excl;
    if (base + 1 < NN) offsets[base + 1] = excl + p1;
    if (base + 2 < NN) offsets[base + 2] = excl + p2;
    if (base + 3 < NN) offsets[base + 3] = excl + p3;
    if (b == 0 && t == 0) offsets[NN] = EE;
}

__global__ __launch_bounds__(256) void k_scatter(const int* __restrict__ src,
                                                 const int* __restrict__ dst,
                                                 const int* __restrict__ offsets,
                                                 int* __restrict__ cursor,
                                                 const float* __restrict__ dinv,
                                                 int* __restrict__ ssrc,
                                                 float* __restrict__ scoef) {
    int e = blockIdx.x * 256 + threadIdx.x;
    if (e >= EE) return;
    int d = dst[e], s = src[e];
    int p = offsets[d] + atomicAdd(&cursor[d], 1);
    ssrc[p] = s;
    scoef[p] = dinv[s] * dinv[d];
}

// ---------------- weight convert: W[K,N] fp32 -> Wt[N,K] bf16 ----------------

__global__ __launch_bounds__(256) void k_wt(const float* __restrict__ W,
                                            unsigned short* __restrict__ Wt,
                                            int K, int N) {
    int i = blockIdx.x * 256 + threadIdx.x;
    if (i >= K * N) return;
    int k = i / N, n = i % N;
    Wt[(size_t)n * K + k] = bf16_rn(W[i]);
}

// ---------------- bf16 MFMA GEMM: C[M,Ntot] = A[M,K] @ Wt^T (+bias)(+relu) ---------
// block 256 = 4 waves; tile 128 x BN; wave = 64 x (TN*16); 16x16x32 MFMA.
// A row-major (bf16 or fp32-converted); Wt is [N,K] bf16 (pre-transposed).

template <int K, int BN, int TN, int ACT, int OUTB, int AF32>
__global__ __launch_bounds__(256) void k_mfma(const void* __restrict__ Ap,
                                              const unsigned short* __restrict__ Wt,
                                              const float* __restrict__ bias,
                                              void* __restrict__ Cp,
                                              int M, int Ntot) {
    constexpr int TM = 4;
    __shared__ unsigned short Al[128][72];  // +8 pad: 144B row = 36 banks -> 2-way max
    __shared__ unsigned short Bl[BN][72];
    const int t = threadIdx.x;
    const int lane = t & 63, wave = t >> 6;
    const int ln = lane & 15, q8 = (lane >> 4) * 8;
    const int row0 = blockIdx.x * 128;
    const int col0 = blockIdx.y * BN;
    const int wm0 = (wave >> 1) * 64;
    const int wn0 = (wave & 1) * (TN * 16);
    f32x4 acc[TM][TN];
#pragma unroll
    for (int i = 0; i < TM; i++)
#pragma unroll
        for (int j = 0; j < TN; j++) acc[i][j] = (f32x4){0.f, 0.f, 0.f, 0.f};

    for (int k0 = 0; k0 < K; k0 += 64) {
#pragma unroll
        for (int it = 0; it < 4; it++) {                 // A tile 128x64
            int c = it * 256 + t;
            int r = c >> 3, cc = (c & 7) * 8;
            int grow = row0 + r;
            if (AF32) {
                const float* A = (const float*)Ap;
                union { unsigned short u[8]; short8 v; } tm8;
                if (grow < M) {
                    float4 v0 = *(const float4*)&A[(size_t)grow * K + k0 + cc];
                    float4 v1 = *(const float4*)&A[(size_t)grow * K + k0 + cc + 4];
                    tm8.u[0] = bf16_rn(v0.x); tm8.u[1] = bf16_rn(v0.y);
                    tm8.u[2] = bf16_rn(v0.z); tm8.u[3] = bf16_rn(v0.w);
                    tm8.u[4] = bf16_rn(v1.x); tm8.u[5] = bf16_rn(v1.y);
                    tm8.u[6] = bf16_rn(v1.z); tm8.u[7] = bf16_rn(v1.w);
                } else {
                    tm8.v = (short8){0, 0, 0, 0, 0, 0, 0, 0};
                }
                *(short8*)&Al[r][cc] = tm8.v;
            } else {
                const unsigned short* A = (const unsigned short*)Ap;
                short8 v = (short8){0, 0, 0, 0, 0, 0, 0, 0};
                if (grow < M) v = *(const short8*)&A[(size_t)grow * K + k0 + cc];
                *(short8*)&Al[r][cc] = v;
            }
        }
#pragma unroll
        for (int it = 0; it < BN / 32; it++) {           // B tile BNx64
            int c = it * 256 + t;
            int r = c >> 3, cc = (c & 7) * 8;
            *(short8*)&Bl[r][cc] = *(const short8*)&Wt[(size_t)(col0 + r) * K + k0 + cc];
        }
        __syncthreads();
#pragma unroll
        for (int ks = 0; ks < 64; ks += 32) {
            short8 af[TM], bfr[TN];
#pragma unroll
            for (int i = 0; i < TM; i++)
                af[i] = *(const short8*)&Al[wm0 + i * 16 + ln][ks + q8];
#pragma unroll
            for (int j = 0; j < TN; j++)
                bfr[j] = *(const short8*)&Bl[wn0 + j * 16 + ln][ks + q8];
#pragma unroll
            for (int i = 0; i < TM; i++)
#pragma unroll
                for (int j = 0; j < TN; j++)
                    acc[i][j] = __builtin_amdgcn_mfma_f32_16x16x32_bf16(af[i], bfr[j], acc[i][j], 0, 0, 0);
        }
        __syncthreads();
    }
    const int qr = (lane >> 4) * 4;
#pragma unroll
    for (int i = 0; i < TM; i++) {
#pragma unroll
        for (int j = 0; j < TN; j++) {
            int col = col0 + wn0 + j * 16 + ln;
            float bv = bias ? bias[col] : 0.f;
#pragma unroll
            for (int r = 0; r < 4; r++) {
                int row = row0 + wm0 + i * 16 + qr + r;
                if (row < M) {
                    float v = acc[i][j][r] + bv;
                    if (ACT) v = fmaxf(v, 0.f);
                    if (OUTB) ((unsigned short*)Cp)[(size_t)row * Ntot + col] = bf16_rn(v);
                    else      ((float*)Cp)[(size_t)row * Ntot + col] = v;
                }
            }
        }
    }
}

// ---------------- head1: fused gather A (h[o]|h[d]|temporal|mode), K=448, N=256 -----

__global__ __launch_bounds__(256) void k_head1m(const unsigned short* __restrict__ hb,
                                                const unsigned short* __restrict__ tmp,
                                                const int* __restrict__ orig,
                                                const int* __restrict__ dest,
                                                const int* __restrict__ mode_ids,
                                                const float* __restrict__ mode_table,
                                                const unsigned short* __restrict__ Wt,
                                                const float* __restrict__ bias,
                                                unsigned short* __restrict__ z1) {
    constexpr int TM = 4, TN = 4;
    __shared__ unsigned short Al[128][72];
    __shared__ unsigned short Bl[128][72];
    __shared__ int io[128], idd[128], im[128];
    const int t = threadIdx.x;
    const int lane = t & 63, wave = t >> 6;
    const int ln = lane & 15, q8 = (lane >> 4) * 8;
    const int row0 = blockIdx.x * 128;
    const int col0 = blockIdx.y * 128;
    const int wm0 = (wave >> 1) * 64, wn0 = (wave & 1) * 64;
    if (t < 128) {
        io[t] = orig[row0 + t];
        idd[t] = dest[row0 + t];
        im[t] = mode_ids[row0 + t];
    }
    f32x4 acc[TM][TN];
#pragma unroll
    for (int i = 0; i < TM; i++)
#pragma unroll
        for (int j = 0; j < TN; j++) acc[i][j] = (f32x4){0.f, 0.f, 0.f, 0.f};
    __syncthreads();

    for (int k0 = 0; k0 < 448; k0 += 64) {
#pragma unroll
        for (int it = 0; it < 4; it++) {
            int c = it * 256 + t;
            int r = c >> 3, cc = (c & 7) * 8;
            int gk = k0 + cc;
            short8 v;
            if (gk < 128)       v = *(const short8*)&hb[(size_t)io[r] * 128 + gk];
            else if (gk < 256)  v = *(const short8*)&hb[(size_t)idd[r] * 128 + (gk - 128)];
            else if (gk < 384)  v = *(const short8*)&tmp[(size_t)(row0 + r) * 128 + (gk - 256)];
            else {
                const float* mp = &mode_table[(size_t)im[r] * 64 + (gk - 384)];
                float4 v0 = *(const float4*)mp;
                float4 v1 = *(const float4*)(mp + 4);
                union { unsigned short u[8]; short8 v; } tm8;
                tm8.u[0] = bf16_rn(v0.x); tm8.u[1] = bf16_rn(v0.y);
                tm8.u[2] = bf16_rn(v0.z); tm8.u[3] = bf16_rn(v0.w);
                tm8.u[4] = bf16_rn(v1.x); tm8.u[5] = bf16_rn(v1.y);
                tm8.u[6] = bf16_rn(v1.z); tm8.u[7] = bf16_rn(v1.w);
                v = tm8.v;
            }
            *(short8*)&Al[r][cc] = v;
        }
#pragma unroll
        for (int it = 0; it < 4; it++) {
            int c = it * 256 + t;
            int r = c >> 3, cc = (c & 7) * 8;
            *(short8*)&Bl[r][cc] = *(const short8*)&Wt[(size_t)(col0 + r) * 448 + k0 + cc];
        }
        __syncthreads();
#pragma unroll
        for (int ks = 0; ks < 64; ks += 32) {
            short8 af[TM], bfr[TN];
#pragma unroll
            for (int i = 0; i < TM; i++)
                af[i] = *(const short8*)&Al[wm0 + i * 16 + ln][ks + q8];
#pragma unroll
            for (int j = 0; j < TN; j++)
                bfr[j] = *(const short8*)&Bl[wn0 + j * 16 + ln][ks + q8];
#pragma unroll
            for (int i = 0; i < TM; i++)
#pragma unroll
                for (int j = 0; j < TN; j++)
                    acc[i][j] = __builtin_amdgcn_mfma_f32_16x16x32_bf16(af[i], bfr[j], acc[i][j], 0, 0, 0);
        }
        __syncthreads();
    }
    const int qr = (lane >> 4) * 4;
#pragma unroll
    for (int i = 0; i < TM; i++) {
#pragma unroll
        for (int j = 0; j < TN; j++) {
            int col = col0 + wn0 + j * 16 + ln;
            float bv = bias[col];
#pragma unroll
            for (int r = 0; r < 4; r++) {
                int row = row0 + wm0 + i * 16 + qr + r;
                float v = fmaxf(acc[i][j][r] + bv, 0.f);
                z1[(size_t)row * 256 + col] = bf16_rn(v);
            }
        }
    }
}

// ---------------- edge aggregation (bf16 in/out, fp32 accumulate) -------------------

__global__ __launch_bounds__(256) void k_agg(const unsigned short* __restrict__ hwb,
                                             const int* __restrict__ ssrc,
                                             const float* __restrict__ scoef,
                                             const int* __restrict__ offsets,
                                             const float* __restrict__ dinv,
                                             const float* __restrict__ bias,
                                             unsigned short* __restrict__ out) {
    int node = blockIdx.x * 4 + (threadIdx.x >> 6);
    int lane = threadIdx.x & 63;
    if (node >= NN) return;
    float di = dinv[node];
    unsigned sv = *(const unsigned*)&hwb[(size_t)node * 128 + 2 * lane];
    float ax = bf2f((unsigned short)sv) * di * di;
    float ay = bf2f((unsigned short)(sv >> 16)) * di * di;
    int beg = offsets[node], end = offsets[node + 1];
    for (int e = beg; e < end; e++) {
        int s = ssrc[e];
        float c = scoef[e];
        unsigned v = *(const unsigned*)&hwb[(size_t)s * 128 + 2 * lane];
        ax = fmaf(bf2f((unsigned short)v), c, ax);
        ay = fmaf(bf2f((unsigned short)(v >> 16)), c, ay);
    }
    float2 bb = ((const float2*)bias)[lane];
    ax = fmaxf(ax + bb.x, 0.f);
    ay = fmaxf(ay + bb.y, 0.f);
    unsigned o = (unsigned)bf16_rn(ax) | ((unsigned)bf16_rn(ay) << 16);
    ((unsigned*)out)[(size_t)node * 64 + lane] = o;
}

// ---------------- temporal-input gather -> bf16 -------------------------------------

__global__ __launch_bounds__(256) void k_tin(const int* __restrict__ day_ids,
                                             const int* __restrict__ time_ids,
                                             const float* __restrict__ day_table,
                                             const float* __restrict__ time_table,
                                             unsigned short* __restrict__ tin) {
    int idx = blockIdx.x * 256 + threadIdx.x;
    int r = idx >> 4, q = idx & 15;
    if (r >= BQ) return;
    const float* src = (q < 8) ? &day_table[(size_t)day_ids[r] * 64 + q * 8]
                               : &time_table[(size_t)time_ids[r] * 64 + (q - 8) * 8];
    float4 v0 = *(const float4*)src;
    float4 v1 = *(const float4*)(src + 4);
    union { unsigned short u[8]; short8 v; } tm8;
    tm8.u[0] = bf16_rn(v0.x); tm8.u[1] = bf16_rn(v0.y);
    tm8.u[2] = bf16_rn(v0.z); tm8.u[3] = bf16_rn(v0.w);
    tm8.u[4] = bf16_rn(v1.x); tm8.u[5] = bf16_rn(v1.y);
    tm8.u[6] = bf16_rn(v1.z); tm8.u[7] = bf16_rn(v1.w);
    *(short8*)&tin[(size_t)r * 128 + q * 8] = tm8.v;
}

// ---------------- head4: [B,64] @ [64,1] + sigmoid ----------------------------------

__global__ __launch_bounds__(256) void k_head4(const float* __restrict__ z3,
                                               const float* __restrict__ Wh4,
                                               const float* __restrict__ bh4,
                                               float* __restrict__ out) {
    __shared__ float w[64];
    int t = threadIdx.x;
    if (t < 64) w[t] = Wh4[t];
    __syncthreads();
    int r = blockIdx.x * 16 + (t / 16);
    int q = t % 16;
    const float4* z4 = (const float4*)z3;
    float4 v = z4[(size_t)r * 16 + q];
    float4 wq = *(const float4*)&w[4 * q];
    float s = v.x * wq.x + v.y * wq.y + v.z * wq.z + v.w * wq.w;
#pragma unroll
    for (int off = 1; off < 16; off <<= 1) s += __shfl_xor(s, off, 64);
    if (q == 0) out[r] = 1.0f / (1.0f + expf(-(s + bh4[0])));
}

// ---------------- launch ------------------------------------------------------------

extern "C" void kernel_launch(void* const* d_in, const int* in_sizes, int n_in,
                              void* d_out, int out_size, void* d_ws, size_t ws_size,
                              hipStream_t stream) {
    const float* x          = (const float*)d_in[0];
    const int*   eidx       = (const int*)d_in[1];
    const int*   esrc       = eidx;
    const int*   edst       = eidx + EE;
    const int*   origin     = (const int*)d_in[2];
    const int*   destid     = (const int*)d_in[3];
    const int*   day_ids    = (const int*)d_in[4];
    const int*   time_ids   = (const int*)d_in[5];
    const int*   mode_ids   = (const int*)d_in[6];
    const float* W1 = (const float*)d_in[7];   const float* b1 = (const float*)d_in[8];
    const float* W2 = (const float*)d_in[9];   const float* b2 = (const float*)d_in[10];
    const float* W3 = (const float*)d_in[11];  const float* b3 = (const float*)d_in[12];
    const float* day_table  = (const float*)d_in[13];
    const float* time_table = (const float*)d_in[14];
    const float* mode_table = (const float*)d_in[15];
    const float* Wf  = (const float*)d_in[16]; const float* bf  = (const float*)d_in[17];
    const float* Wh1 = (const float*)d_in[18]; const float* bh1 = (const float*)d_in[19];
    const float* Wh2 = (const float*)d_in[20]; const float* bh2 = (const float*)d_in[21];
    const float* Wh3 = (const float*)d_in[22]; const float* bh3 = (const float*)d_in[23];
    const float* Wh4 = (const float*)d_in[24]; const float* bh4 = (const float*)d_in[25];
    float* out = (float*)d_out;

    char* wsb = (char*)d_ws;
    size_t off = 0;
    auto alloc = [&](size_t bytes) -> char* {
        char* p = wsb + off;
        off = (off + bytes + 511) & ~(size_t)511;
        return p;
    };
    int*   counts  = (int*)alloc((size_t)NN * 4);
    int*   cursor  = (int*)alloc((size_t)NN * 4);
    int*   offsets = (int*)alloc((size_t)(NN + 1) * 4);
    int*   bsum    = (int*)alloc(128 * 4);
    float* dinv    = (float*)alloc((size_t)NN * 4);
    int*   ssrc    = (int*)alloc((size_t)EE * 4);
    float* scoef   = (float*)alloc((size_t)EE * 4);
    unsigned short* Wt1  = (unsigned short*)alloc(128 * 128 * 2);
    unsigned short* Wt2  = (unsigned short*)alloc(128 * 128 * 2);
    unsigned short* Wt3  = (unsigned short*)alloc(128 * 128 * 2);
    unsigned short* Wtf  = (unsigned short*)alloc(128 * 128 * 2);
    unsigned short* Wth1 = (unsigned short*)alloc(256 * 448 * 2);
    unsigned short* Wth2 = (unsigned short*)alloc(128 * 256 * 2);
    unsigned short* Wth3 = (unsigned short*)alloc(64 * 128 * 2);
    unsigned short* bufHW = (unsigned short*)alloc((size_t)NN * 128 * 2);
    unsigned short* bufH  = (unsigned short*)alloc((size_t)NN * 128 * 2);
    unsigned short* tin   = (unsigned short*)alloc((size_t)BQ * 128 * 2);
    unsigned short* temporal = (unsigned short*)alloc((size_t)BQ * 128 * 2);
    unsigned short* z1 = (unsigned short*)alloc((size_t)BQ * 256 * 2);
    float* z3 = (float*)alloc((size_t)BQ * 64 * 4);
    unsigned short* z2 = tin;  // tin dead after Wf GEMM

    hipMemsetAsync(counts, 0, (size_t)NN * 4, stream);
    hipMemsetAsync(cursor, 0, (size_t)NN * 4, stream);
    k_hist<<<(EE + 255) / 256, 256, 0, stream>>>(edst, counts);
    k_dinv<<<(NN + 255) / 256, 256, 0, stream>>>(counts, dinv);
    const int NCH = (NN + 1023) / 1024;
    k_scan1<<<NCH, 256, 0, stream>>>(counts, bsum);
    k_scan2<<<1, 64, 0, stream>>>(bsum, NCH);
    k_scan3<<<NCH, 256, 0, stream>>>(counts, bsum, offsets);
    k_scatter<<<(EE + 255) / 256, 256, 0, stream>>>(esrc, edst, offsets, cursor, dinv, ssrc, scoef);

    k_wt<<<(128 * 128 + 255) / 256, 256, 0, stream>>>(W1, Wt1, 128, 128);
    k_wt<<<(128 * 128 + 255) / 256, 256, 0, stream>>>(W2, Wt2, 128, 128);
    k_wt<<<(128 * 128 + 255) / 256, 256, 0, stream>>>(W3, Wt3, 128, 128);
    k_wt<<<(128 * 128 + 255) / 256, 256, 0, stream>>>(Wf, Wtf, 128, 128);
    k_wt<<<(448 * 256 + 255) / 256, 256, 0, stream>>>(Wh1, Wth1, 448, 256);
    k_wt<<<(256 * 128 + 255) / 256, 256, 0, stream>>>(Wh2, Wth2, 256, 128);
    k_wt<<<(128 * 64 + 255) / 256, 256, 0, stream>>>(Wh3, Wth3, 128, 64);

    const int GB = (NN + 127) / 128;  // 782
    k_mfma<128, 128, 4, 0, 1, 1><<<dim3(GB, 1), 256, 0, stream>>>(x, Wt1, nullptr, bufHW, NN, 128);
    k_agg<<<(NN + 3) / 4, 256, 0, stream>>>(bufHW, ssrc, scoef, offsets, dinv, b1, bufH);
    k_mfma<128, 128, 4, 0, 1, 0><<<dim3(GB, 1), 256, 0, stream>>>(bufH, Wt2, nullptr, bufHW, NN, 128);
    k_agg<<<(NN + 3) / 4, 256, 0, stream>>>(bufHW, ssrc, scoef, offsets, dinv, b2, bufH);
    k_mfma<128, 128, 4, 0, 1, 0><<<dim3(GB, 1), 256, 0, stream>>>(bufH, Wt3, nullptr, bufHW, NN, 128);
    k_agg<<<(NN + 3) / 4, 256, 0, stream>>>(bufHW, ssrc, scoef, offsets, dinv, b3, bufH);
    // final h = bufH (bf16)

    k_tin<<<(BQ * 16) / 256, 256, 0, stream>>>(day_ids, time_ids, day_table, time_table, tin);
    k_mfma<128, 128, 4, 1, 1, 0><<<dim3(BQ / 128, 1), 256, 0, stream>>>(tin, Wtf, bf, temporal, BQ, 128);
    k_head1m<<<dim3(BQ / 128, 2), 256, 0, stream>>>(bufH, temporal, origin, destid, mode_ids,
                                                    mode_table, Wth1, bh1, z1);
    k_mfma<256, 128, 4, 1, 1, 0><<<dim3(BQ / 128, 1), 256, 0, stream>>>(z1, Wth2, bh2, z2, BQ, 128);
    k_mfma<128, 64, 2, 1, 0, 0><<<dim3(BQ / 128, 1), 256, 0, stream>>>(z2, Wth3, bh3, z3, BQ, 64);
    k_head4<<<BQ / 16, 256, 0, stream>>>(z3, Wh4, bh4, out);
}

// Round 3
// 671.940 us; speedup vs baseline: 2.0838x; 1.4747x over previous
//
#include <hip/hip_runtime.h>

#define NN 100000   // nodes
#define EE 1600000  // edges
#define BQ 65536    // queries

typedef __attribute__((ext_vector_type(8))) short short8;
typedef __attribute__((ext_vector_type(4))) float f32x4;

__device__ __forceinline__ unsigned short bf16_rn(float f) {
    unsigned u = __builtin_bit_cast(unsigned, f);
    u += 0x7fff + ((u >> 16) & 1);
    return (unsigned short)(u >> 16);
}
__device__ __forceinline__ float bf2f(unsigned short h) {
    unsigned u = ((unsigned)h) << 16;
    return __builtin_bit_cast(float, u);
}

// ---------------- degree / sort-by-dst machinery ----------------

__global__ __launch_bounds__(256) void k_hist(const int* __restrict__ dst,
                                              int* __restrict__ counts) {
    int i = blockIdx.x * 256 + threadIdx.x;
    if (i < EE) atomicAdd(&counts[dst[i]], 1);
}

__global__ __launch_bounds__(256) void k_dinv(const int* __restrict__ counts,
                                              float* __restrict__ dinv) {
    int i = blockIdx.x * 256 + threadIdx.x;
    if (i < NN) dinv[i] = rsqrtf((float)counts[i] + 1.0f);
}

__global__ __launch_bounds__(256) void k_scan1(const int* __restrict__ counts,
                                               int* __restrict__ bsum) {
    __shared__ int sd[256];
    int t = threadIdx.x, b = blockIdx.x;
    int s = 0;
#pragma unroll
    for (int j = 0; j < 4; j++) {
        int i = b * 1024 + t + 256 * j;
        if (i < NN) s += counts[i];
    }
    sd[t] = s;
    __syncthreads();
    for (int o = 128; o > 0; o >>= 1) {
        if (t < o) sd[t] += sd[t + o];
        __syncthreads();
    }
    if (t == 0) bsum[b] = sd[0];
}

__global__ void k_scan2(int* bsum, int nch) {
    if (threadIdx.x == 0 && blockIdx.x == 0) {
        int run = 0;
        for (int i = 0; i < nch; i++) { int v = bsum[i]; bsum[i] = run; run += v; }
    }
}

__global__ __launch_bounds__(256) void k_scan3(const int* __restrict__ counts,
                                               const int* __restrict__ bsum,
                                               int* __restrict__ offsets) {
    __shared__ int sd[256];
    int t = threadIdx.x, b = blockIdx.x;
    int base = b * 1024 + 4 * t;
    int v0 = (base + 0 < NN) ? counts[base + 0] : 0;
    int v1 = (base + 1 < NN) ? counts[base + 1] : 0;
    int v2 = (base + 2 < NN) ? counts[base + 2] : 0;
    int v3 = (base + 3 < NN) ? counts[base + 3] : 0;
    int p1 = v0, p2 = p1 + v1, p3 = p2 + v2, ts = p3 + v3;
    sd[t] = ts;
    __syncthreads();
    for (int o = 1; o < 256; o <<= 1) {
        int x = (t >= o) ? sd[t - o] : 0;
        __syncthreads();
        sd[t] += x;
        __syncthreads();
    }
    int excl = sd[t] - ts + bsum[b];
    if (base + 0 < NN) offsets[base + 0] = excl;
    if (base + 1 < NN) offsets[base + 1] = excl + p1;
    if (base + 2 < NN) offsets[base + 2] = excl + p2;
    if (base + 3 < NN) offsets[base + 3] = excl + p3;
    if (b == 0 && t == 0) offsets[NN] = EE;
}

__global__ __launch_bounds__(256) void k_scatter(const int* __restrict__ src,
                                                 const int* __restrict__ dst,
                                                 const int* __restrict__ offsets,
                                                 int* __restrict__ cursor,
                                                 const float* __restrict__ dinv,
                                                 int2* __restrict__ epair) {
    int e = blockIdx.x * 256 + threadIdx.x;
    if (e >= EE) return;
    int d = dst[e], s = src[e];
    int p = offsets[d] + atomicAdd(&cursor[d], 1);
    float c = dinv[s] * dinv[d];
    epair[p] = make_int2(s, __builtin_bit_cast(int, c));
}

// ---------------- fused weight convert: all W[K,N] fp32 -> Wt[N,K] bf16 -------------

__global__ __launch_bounds__(256) void k_wtall(const float* __restrict__ W1,
                                               const float* __restrict__ W2,
                                               const float* __restrict__ W3,
                                               const float* __restrict__ Wf,
                                               const float* __restrict__ Wh1,
                                               const float* __restrict__ Wh2,
                                               const float* __restrict__ Wh3,
                                               unsigned short* __restrict__ Wt1,
                                               unsigned short* __restrict__ Wt2,
                                               unsigned short* __restrict__ Wt3,
                                               unsigned short* __restrict__ Wtf,
                                               unsigned short* __restrict__ Wth1,
                                               unsigned short* __restrict__ Wth2,
                                               unsigned short* __restrict__ Wth3) {
    int i = blockIdx.x * 256 + threadIdx.x;
    const float* W; unsigned short* Wt; int K, N, idx;
    if (i < 16384)       { W = W1;  Wt = Wt1;  K = 128; N = 128; idx = i; }
    else if (i < 32768)  { W = W2;  Wt = Wt2;  K = 128; N = 128; idx = i - 16384; }
    else if (i < 49152)  { W = W3;  Wt = Wt3;  K = 128; N = 128; idx = i - 32768; }
    else if (i < 65536)  { W = Wf;  Wt = Wtf;  K = 128; N = 128; idx = i - 49152; }
    else if (i < 180224) { W = Wh1; Wt = Wth1; K = 448; N = 256; idx = i - 65536; }
    else if (i < 212992) { W = Wh2; Wt = Wth2; K = 256; N = 128; idx = i - 180224; }
    else if (i < 221184) { W = Wh3; Wt = Wth3; K = 128; N = 64;  idx = i - 212992; }
    else return;
    int k = idx / N, n = idx % N;
    Wt[(size_t)n * K + k] = bf16_rn(W[idx]);
}

// ---------------- bf16 MFMA GEMM: C[M,Ntot] = A[M,K] @ Wt^T (+bias)(+relu) ---------

template <int K, int BN, int TN, int ACT, int OUTB, int AF32>
__global__ __launch_bounds__(256) void k_mfma(const void* __restrict__ Ap,
                                              const unsigned short* __restrict__ Wt,
                                              const float* __restrict__ bias,
                                              void* __restrict__ Cp,
                                              int M, int Ntot) {
    constexpr int TM = 4;
    __shared__ unsigned short Al[128][72];
    __shared__ unsigned short Bl[BN][72];
    const int t = threadIdx.x;
    const int lane = t & 63, wave = t >> 6;
    const int ln = lane & 15, q8 = (lane >> 4) * 8;
    const int row0 = blockIdx.x * 128;
    const int col0 = blockIdx.y * BN;
    const int wm0 = (wave >> 1) * 64;
    const int wn0 = (wave & 1) * (TN * 16);
    f32x4 acc[TM][TN];
#pragma unroll
    for (int i = 0; i < TM; i++)
#pragma unroll
        for (int j = 0; j < TN; j++) acc[i][j] = (f32x4){0.f, 0.f, 0.f, 0.f};

    for (int k0 = 0; k0 < K; k0 += 64) {
#pragma unroll
        for (int it = 0; it < 4; it++) {
            int c = it * 256 + t;
            int r = c >> 3, cc = (c & 7) * 8;
            int grow = row0 + r;
            if (AF32) {
                const float* A = (const float*)Ap;
                union { unsigned short u[8]; short8 v; } tm8;
                if (grow < M) {
                    float4 v0 = *(const float4*)&A[(size_t)grow * K + k0 + cc];
                    float4 v1 = *(const float4*)&A[(size_t)grow * K + k0 + cc + 4];
                    tm8.u[0] = bf16_rn(v0.x); tm8.u[1] = bf16_rn(v0.y);
                    tm8.u[2] = bf16_rn(v0.z); tm8.u[3] = bf16_rn(v0.w);
                    tm8.u[4] = bf16_rn(v1.x); tm8.u[5] = bf16_rn(v1.y);
                    tm8.u[6] = bf16_rn(v1.z); tm8.u[7] = bf16_rn(v1.w);
                } else {
                    tm8.v = (short8){0, 0, 0, 0, 0, 0, 0, 0};
                }
                *(short8*)&Al[r][cc] = tm8.v;
            } else {
                const unsigned short* A = (const unsigned short*)Ap;
                short8 v = (short8){0, 0, 0, 0, 0, 0, 0, 0};
                if (grow < M) v = *(const short8*)&A[(size_t)grow * K + k0 + cc];
                *(short8*)&Al[r][cc] = v;
            }
        }
#pragma unroll
        for (int it = 0; it < BN / 32; it++) {
            int c = it * 256 + t;
            int r = c >> 3, cc = (c & 7) * 8;
            *(short8*)&Bl[r][cc] = *(const short8*)&Wt[(size_t)(col0 + r) * K + k0 + cc];
        }
        __syncthreads();
#pragma unroll
        for (int ks = 0; ks < 64; ks += 32) {
            short8 af[TM], bfr[TN];
#pragma unroll
            for (int i = 0; i < TM; i++)
                af[i] = *(const short8*)&Al[wm0 + i * 16 + ln][ks + q8];
#pragma unroll
            for (int j = 0; j < TN; j++)
                bfr[j] = *(const short8*)&Bl[wn0 + j * 16 + ln][ks + q8];
#pragma unroll
            for (int i = 0; i < TM; i++)
#pragma unroll
                for (int j = 0; j < TN; j++)
                    acc[i][j] = __builtin_amdgcn_mfma_f32_16x16x32_bf16(af[i], bfr[j], acc[i][j], 0, 0, 0);
        }
        __syncthreads();
    }
    const int qr = (lane >> 4) * 4;
#pragma unroll
    for (int i = 0; i < TM; i++) {
#pragma unroll
        for (int j = 0; j < TN; j++) {
            int col = col0 + wn0 + j * 16 + ln;
            float bv = bias ? bias[col] : 0.f;
#pragma unroll
            for (int r = 0; r < 4; r++) {
                int row = row0 + wm0 + i * 16 + qr + r;
                if (row < M) {
                    float v = acc[i][j][r] + bv;
                    if (ACT) v = fmaxf(v, 0.f);
                    if (OUTB) ((unsigned short*)Cp)[(size_t)row * Ntot + col] = bf16_rn(v);
                    else      ((float*)Cp)[(size_t)row * Ntot + col] = v;
                }
            }
        }
    }
}

// ---------------- temporal GEMM with fused embedding gather: K=128 -> N=128 ---------

__global__ __launch_bounds__(256) void k_tempm(const int* __restrict__ day_ids,
                                               const int* __restrict__ time_ids,
                                               const float* __restrict__ day_table,
                                               const float* __restrict__ time_table,
                                               const unsigned short* __restrict__ Wt,
                                               const float* __restrict__ bias,
                                               unsigned short* __restrict__ Cout) {
    constexpr int TM = 4, TN = 4;
    __shared__ unsigned short Al[128][72];
    __shared__ unsigned short Bl[128][72];
    __shared__ int dayl[128], timel[128];
    const int t = threadIdx.x;
    const int lane = t & 63, wave = t >> 6;
    const int ln = lane & 15, q8 = (lane >> 4) * 8;
    const int row0 = blockIdx.x * 128;
    const int wm0 = (wave >> 1) * 64, wn0 = (wave & 1) * 64;
    if (t < 128) { dayl[t] = day_ids[row0 + t]; timel[t] = time_ids[row0 + t]; }
    f32x4 acc[TM][TN];
#pragma unroll
    for (int i = 0; i < TM; i++)
#pragma unroll
        for (int j = 0; j < TN; j++) acc[i][j] = (f32x4){0.f, 0.f, 0.f, 0.f};
    __syncthreads();

    for (int k0 = 0; k0 < 128; k0 += 64) {
        const float* tab = k0 ? time_table : day_table;
        const int*   ids = k0 ? timel : dayl;
#pragma unroll
        for (int it = 0; it < 4; it++) {
            int c = it * 256 + t;
            int r = c >> 3, cc = (c & 7) * 8;
            const float* p = &tab[(size_t)ids[r] * 64 + cc];
            float4 v0 = *(const float4*)p;
            float4 v1 = *(const float4*)(p + 4);
            union { unsigned short u[8]; short8 v; } tm8;
            tm8.u[0] = bf16_rn(v0.x); tm8.u[1] = bf16_rn(v0.y);
            tm8.u[2] = bf16_rn(v0.z); tm8.u[3] = bf16_rn(v0.w);
            tm8.u[4] = bf16_rn(v1.x); tm8.u[5] = bf16_rn(v1.y);
            tm8.u[6] = bf16_rn(v1.z); tm8.u[7] = bf16_rn(v1.w);
            *(short8*)&Al[r][cc] = tm8.v;
        }
#pragma unroll
        for (int it = 0; it < 4; it++) {
            int c = it * 256 + t;
            int r = c >> 3, cc = (c & 7) * 8;
            *(short8*)&Bl[r][cc] = *(const short8*)&Wt[(size_t)r * 128 + k0 + cc];
        }
        __syncthreads();
#pragma unroll
        for (int ks = 0; ks < 64; ks += 32) {
            short8 af[TM], bfr[TN];
#pragma unroll
            for (int i = 0; i < TM; i++)
                af[i] = *(const short8*)&Al[wm0 + i * 16 + ln][ks + q8];
#pragma unroll
            for (int j = 0; j < TN; j++)
                bfr[j] = *(const short8*)&Bl[wn0 + j * 16 + ln][ks + q8];
#pragma unroll
            for (int i = 0; i < TM; i++)
#pragma unroll
                for (int j = 0; j < TN; j++)
                    acc[i][j] = __builtin_amdgcn_mfma_f32_16x16x32_bf16(af[i], bfr[j], acc[i][j], 0, 0, 0);
        }
        __syncthreads();
    }
    const int qr = (lane >> 4) * 4;
#pragma unroll
    for (int i = 0; i < TM; i++) {
#pragma unroll
        for (int j = 0; j < TN; j++) {
            int col = wn0 + j * 16 + ln;
            float bv = bias[col];
#pragma unroll
            for (int r = 0; r < 4; r++) {
                int row = row0 + wm0 + i * 16 + qr + r;
                float v = fmaxf(acc[i][j][r] + bv, 0.f);
                Cout[(size_t)row * 128 + col] = bf16_rn(v);
            }
        }
    }
}

// ---------------- head1: fused gather A (h[o]|h[d]|temporal|mode), K=448, N=256 -----

__global__ __launch_bounds__(256) void k_head1m(const unsigned short* __restrict__ hb,
                                                const unsigned short* __restrict__ tmp,
                                                const int* __restrict__ orig,
                                                const int* __restrict__ dest,
                                                const int* __restrict__ mode_ids,
                                                const float* __restrict__ mode_table,
                                                const unsigned short* __restrict__ Wt,
                                                const float* __restrict__ bias,
                                                unsigned short* __restrict__ z1) {
    constexpr int TM = 4, TN = 4;
    __shared__ unsigned short Al[128][72];
    __shared__ unsigned short Bl[128][72];
    __shared__ int io[128], idd[128], im[128];
    const int t = threadIdx.x;
    const int lane = t & 63, wave = t >> 6;
    const int ln = lane & 15, q8 = (lane >> 4) * 8;
    const int row0 = blockIdx.x * 128;
    const int col0 = blockIdx.y * 128;
    const int wm0 = (wave >> 1) * 64, wn0 = (wave & 1) * 64;
    if (t < 128) {
        io[t] = orig[row0 + t];
        idd[t] = dest[row0 + t];
        im[t] = mode_ids[row0 + t];
    }
    f32x4 acc[TM][TN];
#pragma unroll
    for (int i = 0; i < TM; i++)
#pragma unroll
        for (int j = 0; j < TN; j++) acc[i][j] = (f32x4){0.f, 0.f, 0.f, 0.f};
    __syncthreads();

    for (int k0 = 0; k0 < 448; k0 += 64) {
#pragma unroll
        for (int it = 0; it < 4; it++) {
            int c = it * 256 + t;
            int r = c >> 3, cc = (c & 7) * 8;
            int gk = k0 + cc;
            short8 v;
            if (gk < 128)       v = *(const short8*)&hb[(size_t)io[r] * 128 + gk];
            else if (gk < 256)  v = *(const short8*)&hb[(size_t)idd[r] * 128 + (gk - 128)];
            else if (gk < 384)  v = *(const short8*)&tmp[(size_t)(row0 + r) * 128 + (gk - 256)];
            else {
                const float* mp = &mode_table[(size_t)im[r] * 64 + (gk - 384)];
                float4 v0 = *(const float4*)mp;
                float4 v1 = *(const float4*)(mp + 4);
                union { unsigned short u[8]; short8 v; } tm8;
                tm8.u[0] = bf16_rn(v0.x); tm8.u[1] = bf16_rn(v0.y);
                tm8.u[2] = bf16_rn(v0.z); tm8.u[3] = bf16_rn(v0.w);
                tm8.u[4] = bf16_rn(v1.x); tm8.u[5] = bf16_rn(v1.y);
                tm8.u[6] = bf16_rn(v1.z); tm8.u[7] = bf16_rn(v1.w);
                v = tm8.v;
            }
            *(short8*)&Al[r][cc] = v;
        }
#pragma unroll
        for (int it = 0; it < 4; it++) {
            int c = it * 256 + t;
            int r = c >> 3, cc = (c & 7) * 8;
            *(short8*)&Bl[r][cc] = *(const short8*)&Wt[(size_t)(col0 + r) * 448 + k0 + cc];
        }
        __syncthreads();
#pragma unroll
        for (int ks = 0; ks < 64; ks += 32) {
            short8 af[TM], bfr[TN];
#pragma unroll
            for (int i = 0; i < TM; i++)
                af[i] = *(const short8*)&Al[wm0 + i * 16 + ln][ks + q8];
#pragma unroll
            for (int j = 0; j < TN; j++)
                bfr[j] = *(const short8*)&Bl[wn0 + j * 16 + ln][ks + q8];
#pragma unroll
            for (int i = 0; i < TM; i++)
#pragma unroll
                for (int j = 0; j < TN; j++)
                    acc[i][j] = __builtin_amdgcn_mfma_f32_16x16x32_bf16(af[i], bfr[j], acc[i][j], 0, 0, 0);
        }
        __syncthreads();
    }
    const int qr = (lane >> 4) * 4;
#pragma unroll
    for (int i = 0; i < TM; i++) {
#pragma unroll
        for (int j = 0; j < TN; j++) {
            int col = col0 + wn0 + j * 16 + ln;
            float bv = bias[col];
#pragma unroll
            for (int r = 0; r < 4; r++) {
                int row = row0 + wm0 + i * 16 + qr + r;
                float v = fmaxf(acc[i][j][r] + bv, 0.f);
                z1[(size_t)row * 256 + col] = bf16_rn(v);
            }
        }
    }
}

// ---------------- edge aggregation: 4 edges/wave-iter, 16B/lane, unroll x2 ----------
// wave = 1 node; quarter q handles edge e+q; lane l (0..15) covers 16B of the row.

__global__ __launch_bounds__(256) void k_agg(const unsigned short* __restrict__ hwb,
                                             const int2* __restrict__ epair,
                                             const int* __restrict__ offsets,
                                             const float* __restrict__ dinv,
                                             const float* __restrict__ bias,
                                             unsigned short* __restrict__ out) {
    int node = blockIdx.x * 4 + (threadIdx.x >> 6);
    int lane = threadIdx.x & 63;
    if (node >= NN) return;
    const int q = lane >> 4, l = lane & 15;
    float acc[8];
#pragma unroll
    for (int i = 0; i < 8; i++) acc[i] = 0.f;
    const int beg = offsets[node], end = offsets[node + 1];
    int e = beg;
    for (; e + 8 <= end; e += 8) {
        int2 p0 = epair[e + q];
        int2 p1 = epair[e + 4 + q];
        float c0 = __builtin_bit_cast(float, p0.y);
        float c1 = __builtin_bit_cast(float, p1.y);
        short8 v0 = *(const short8*)&hwb[(size_t)p0.x * 128 + l * 8];
        short8 v1 = *(const short8*)&hwb[(size_t)p1.x * 128 + l * 8];
#pragma unroll
        for (int i = 0; i < 8; i++) acc[i] = fmaf(bf2f((unsigned short)v0[i]), c0, acc[i]);
#pragma unroll
        for (int i = 0; i < 8; i++) acc[i] = fmaf(bf2f((unsigned short)v1[i]), c1, acc[i]);
    }
    for (; e < end; e += 4) {
        int ee = e + q;
        int ec = (ee < end) ? ee : (end - 1);
        int2 p = epair[ec];
        float c = (ee < end) ? __builtin_bit_cast(float, p.y) : 0.f;
        short8 v = *(const short8*)&hwb[(size_t)p.x * 128 + l * 8];
#pragma unroll
        for (int i = 0; i < 8; i++) acc[i] = fmaf(bf2f((unsigned short)v[i]), c, acc[i]);
    }
#pragma unroll
    for (int i = 0; i < 8; i++) {
        acc[i] += __shfl_xor(acc[i], 16);
        acc[i] += __shfl_xor(acc[i], 32);
    }
    if (q == 0) {
        float di = dinv[node];
        float dd = di * di;
        short8 hs = *(const short8*)&hwb[(size_t)node * 128 + l * 8];
        float4 b0 = *(const float4*)&bias[l * 8];
        float4 b1 = *(const float4*)&bias[l * 8 + 4];
        float bb[8] = {b0.x, b0.y, b0.z, b0.w, b1.x, b1.y, b1.z, b1.w};
        union { unsigned short u[8]; short8 v; } o;
#pragma unroll
        for (int i = 0; i < 8; i++) {
            float v = fmaf(bf2f((unsigned short)hs[i]), dd, acc[i]) + bb[i];
            o.u[i] = bf16_rn(fmaxf(v, 0.f));
        }
        *(short8*)&out[(size_t)node * 128 + l * 8] = o.v;
    }
}

// ---------------- head4: [B,64] @ [64,1] + sigmoid ----------------------------------

__global__ __launch_bounds__(256) void k_head4(const float* __restrict__ z3,
                                               const float* __restrict__ Wh4,
                                               const float* __restrict__ bh4,
                                               float* __restrict__ out) {
    __shared__ float w[64];
    int t = threadIdx.x;
    if (t < 64) w[t] = Wh4[t];
    __syncthreads();
    int r = blockIdx.x * 16 + (t / 16);
    int q = t % 16;
    const float4* z4 = (const float4*)z3;
    float4 v = z4[(size_t)r * 16 + q];
    float4 wq = *(const float4*)&w[4 * q];
    float s = v.x * wq.x + v.y * wq.y + v.z * wq.z + v.w * wq.w;
#pragma unroll
    for (int off = 1; off < 16; off <<= 1) s += __shfl_xor(s, off, 64);
    if (q == 0) out[r] = 1.0f / (1.0f + expf(-(s + bh4[0])));
}

// ---------------- launch ------------------------------------------------------------

extern "C" void kernel_launch(void* const* d_in, const int* in_sizes, int n_in,
                              void* d_out, int out_size, void* d_ws, size_t ws_size,
                              hipStream_t stream) {
    const float* x          = (const float*)d_in[0];
    const int*   eidx       = (const int*)d_in[1];
    const int*   esrc       = eidx;
    const int*   edst       = eidx + EE;
    const int*   origin     = (const int*)d_in[2];
    const int*   destid     = (const int*)d_in[3];
    const int*   day_ids    = (const int*)d_in[4];
    const int*   time_ids   = (const int*)d_in[5];
    const int*   mode_ids   = (const int*)d_in[6];
    const float* W1 = (const float*)d_in[7];   const float* b1 = (const float*)d_in[8];
    const float* W2 = (const float*)d_in[9];   const float* b2 = (const float*)d_in[10];
    const float* W3 = (const float*)d_in[11];  const float* b3 = (const float*)d_in[12];
    const float* day_table  = (const float*)d_in[13];
    const float* time_table = (const float*)d_in[14];
    const float* mode_table = (const float*)d_in[15];
    const float* Wf  = (const float*)d_in[16]; const float* bf  = (const float*)d_in[17];
    const float* Wh1 = (const float*)d_in[18]; const float* bh1 = (const float*)d_in[19];
    const float* Wh2 = (const float*)d_in[20]; const float* bh2 = (const float*)d_in[21];
    const float* Wh3 = (const float*)d_in[22]; const float* bh3 = (const float*)d_in[23];
    const float* Wh4 = (const float*)d_in[24]; const float* bh4 = (const float*)d_in[25];
    float* out = (float*)d_out;

    char* wsb = (char*)d_ws;
    size_t off = 0;
    auto alloc = [&](size_t bytes) -> char* {
        char* p = wsb + off;
        off = (off + bytes + 511) & ~(size_t)511;
        return p;
    };
    int*   counts  = (int*)alloc((size_t)NN * 4);
    int*   cursor  = (int*)alloc((size_t)NN * 4);
    int*   offsets = (int*)alloc((size_t)(NN + 1) * 4);
    int*   bsum    = (int*)alloc(128 * 4);
    float* dinv    = (float*)alloc((size_t)NN * 4);
    int2*  epair   = (int2*)alloc((size_t)EE * 8);
    unsigned short* Wt1  = (unsigned short*)alloc(128 * 128 * 2);
    unsigned short* Wt2  = (unsigned short*)alloc(128 * 128 * 2);
    unsigned short* Wt3  = (unsigned short*)alloc(128 * 128 * 2);
    unsigned short* Wtf  = (unsigned short*)alloc(128 * 128 * 2);
    unsigned short* Wth1 = (unsigned short*)alloc(256 * 448 * 2);
    unsigned short* Wth2 = (unsigned short*)alloc(128 * 256 * 2);
    unsigned short* Wth3 = (unsigned short*)alloc(64 * 128 * 2);
    unsigned short* bufHW = (unsigned short*)alloc((size_t)NN * 128 * 2);
    unsigned short* bufH  = (unsigned short*)alloc((size_t)NN * 128 * 2);
    unsigned short* temporal = (unsigned short*)alloc((size_t)BQ * 128 * 2);
    unsigned short* z1 = (unsigned short*)alloc((size_t)BQ * 256 * 2);
    float* z3 = (float*)alloc((size_t)BQ * 64 * 4);
    unsigned short* z2 = temporal;  // temporal dead after head1m

    hipMemsetAsync(counts, 0, (size_t)NN * 4, stream);
    hipMemsetAsync(cursor, 0, (size_t)NN * 4, stream);
    k_hist<<<(EE + 255) / 256, 256, 0, stream>>>(edst, counts);
    k_dinv<<<(NN + 255) / 256, 256, 0, stream>>>(counts, dinv);
    const int NCH = (NN + 1023) / 1024;
    k_scan1<<<NCH, 256, 0, stream>>>(counts, bsum);
    k_scan2<<<1, 64, 0, stream>>>(bsum, NCH);
    k_scan3<<<NCH, 256, 0, stream>>>(counts, bsum, offsets);
    k_scatter<<<(EE + 255) / 256, 256, 0, stream>>>(esrc, edst, offsets, cursor, dinv, epair);

    k_wtall<<<(221184 + 255) / 256, 256, 0, stream>>>(W1, W2, W3, Wf, Wh1, Wh2, Wh3,
                                                      Wt1, Wt2, Wt3, Wtf, Wth1, Wth2, Wth3);

    const int GB = (NN + 127) / 128;  // 782
    k_mfma<128, 128, 4, 0, 1, 1><<<dim3(GB, 1), 256, 0, stream>>>(x, Wt1, nullptr, bufHW, NN, 128);
    k_agg<<<(NN + 3) / 4, 256, 0, stream>>>(bufHW, epair, offsets, dinv, b1, bufH);
    k_mfma<128, 128, 4, 0, 1, 0><<<dim3(GB, 1), 256, 0, stream>>>(bufH, Wt2, nullptr, bufHW, NN, 128);
    k_agg<<<(NN + 3) / 4, 256, 0, stream>>>(bufHW, epair, offsets, dinv, b2, bufH);
    k_mfma<128, 128, 4, 0, 1, 0><<<dim3(GB, 1), 256, 0, stream>>>(bufH, Wt3, nullptr, bufHW, NN, 128);
    k_agg<<<(NN + 3) / 4, 256, 0, stream>>>(bufHW, epair, offsets, dinv, b3, bufH);
    // final h = bufH (bf16)

    k_tempm<<<BQ / 128, 256, 0, stream>>>(day_ids, time_ids, day_table, time_table,
                                          Wtf, bf, temporal);
    k_head1m<<<dim3(BQ / 128, 2), 256, 0, stream>>>(bufH, temporal, origin, destid, mode_ids,
                                                    mode_table, Wth1, bh1, z1);
    k_mfma<256, 128, 4, 1, 1, 0><<<dim3(BQ / 128, 1), 256, 0, stream>>>(z1, Wth2, bh2, z2, BQ, 128);
    k_mfma<128, 64, 2, 1, 0, 0><<<dim3(BQ / 128, 1), 256, 0, stream>>>(z2, Wth3, bh3, z3, BQ, 64);
    k_head4<<<BQ / 16, 256, 0, stream>>>(z3, Wh4, bh4, out);
}

// Round 4
// 583.001 us; speedup vs baseline: 2.4017x; 1.1526x over previous
//
#include <hip/hip_runtime.h>

#define NN 100000   // nodes
#define EE 1600000  // edges
#define BQ 65536    // queries
#define NBK 391     // node buckets of 256 (ceil(NN/256))
#define ECH 6250    // edges per binning block (EE/256)

typedef __attribute__((ext_vector_type(8))) short short8;
typedef __attribute__((ext_vector_type(4))) float f32x4;

__device__ __forceinline__ unsigned short bf16_rn(float f) {
    unsigned u = __builtin_bit_cast(unsigned, f);
    u += 0x7fff + ((u >> 16) & 1);
    return (unsigned short)(u >> 16);
}
__device__ __forceinline__ float bf2f(unsigned short h) {
    unsigned u = ((unsigned)h) << 16;
    return __builtin_bit_cast(float, u);
}

// ---------------- bucket count: LDS hist of dst>>8 ----------------------------------

__global__ __launch_bounds__(256) void k_bcount(const int* __restrict__ dst,
                                                int* __restrict__ bcnt) {
    __shared__ int h[NBK];
    int t = threadIdx.x, b = blockIdx.x;
    for (int j = t; j < NBK; j += 256) h[j] = 0;
    __syncthreads();
    int lo = b * ECH, hi = lo + ECH;
    for (int i = lo + t; i < hi; i += 256) atomicAdd(&h[dst[i] >> 8], 1);
    __syncthreads();
    for (int j = t; j < NBK; j += 256)
        if (h[j]) atomicAdd(&bcnt[j], h[j]);
}

// ---------------- bucket scan: bbase = excl scan, init cursor -----------------------

__global__ __launch_bounds__(512) void k_bscan(const int* __restrict__ bcnt,
                                               int* __restrict__ bbase,
                                               int* __restrict__ bcur) {
    __shared__ int sd[512];
    int t = threadIdx.x;
    int v = (t < NBK) ? bcnt[t] : 0;
    sd[t] = v;
    __syncthreads();
    for (int o = 1; o < 512; o <<= 1) {
        int x = (t >= o) ? sd[t - o] : 0;
        __syncthreads();
        sd[t] += x;
        __syncthreads();
    }
    if (t < NBK) { int e = sd[t] - v; bbase[t] = e; bcur[t] = e; }
    if (t == 0) bbase[NBK] = EE;
}

// ---------------- binning: multisplit into 391 buckets, run-coalesced writes --------

__global__ __launch_bounds__(256) void k_bin(const int* __restrict__ src,
                                             const int* __restrict__ dst,
                                             int* __restrict__ bcur,
                                             int2* __restrict__ binned) {
    __shared__ int h[NBK];
    __shared__ int cur[NBK];
    int t = threadIdx.x, b = blockIdx.x;
    for (int j = t; j < NBK; j += 256) { h[j] = 0; cur[j] = 0; }
    __syncthreads();
    int lo = b * ECH, hi = lo + ECH;
    for (int i = lo + t; i < hi; i += 256) atomicAdd(&h[dst[i] >> 8], 1);
    __syncthreads();
    for (int j = t; j < NBK; j += 256)
        if (h[j]) h[j] = atomicAdd(&bcur[j], h[j]);
    __syncthreads();
    for (int i = lo + t; i < hi; i += 256) {
        int d = dst[i], bk = d >> 8;
        int pos = h[bk] + atomicAdd(&cur[bk], 1);
        binned[pos] = make_int2(src[i], d);
    }
}

// ---------------- per-bucket: node offsets + dinv (replaces hist/scan/dinv) ---------

__global__ __launch_bounds__(256) void k_boff(const int2* __restrict__ binned,
                                              const int* __restrict__ bbase,
                                              int* __restrict__ offsets,
                                              float* __restrict__ dinv) {
    __shared__ int lh[256];
    __shared__ int sd[256];
    int t = threadIdx.x, b = blockIdx.x;
    lh[t] = 0;
    __syncthreads();
    int lo = bbase[b], hi = bbase[b + 1];
    for (int i = lo + t; i < hi; i += 256) atomicAdd(&lh[binned[i].y & 255], 1);
    __syncthreads();
    int v = lh[t];
    sd[t] = v;
    __syncthreads();
    for (int o = 1; o < 256; o <<= 1) {
        int x = (t >= o) ? sd[t - o] : 0;
        __syncthreads();
        sd[t] += x;
        __syncthreads();
    }
    int node = (b << 8) + t;
    if (node < NN) {
        offsets[node] = lo + (sd[t] - v);
        dinv[node] = rsqrtf((float)v + 1.0f);
    }
    if (b == NBK - 1 && t == 0) offsets[NN] = EE;
}

// ---------------- placement: bucket-local windows, merged writes --------------------
// epair[p] = (src, dinv[src]); dinv[dst] hoisted into k_agg.

__global__ __launch_bounds__(256) void k_place(const int2* __restrict__ binned,
                                               const int* __restrict__ bbase,
                                               const int* __restrict__ offsets,
                                               const float* __restrict__ dinv,
                                               int2* __restrict__ epair) {
    __shared__ int lcur[256];
    int t = threadIdx.x, b = blockIdx.x;
    int node = (b << 8) + t;
    lcur[t] = (node < NN) ? offsets[node] : 0;
    __syncthreads();
    int lo = bbase[b], hi = bbase[b + 1];
    for (int i = lo + t; i < hi; i += 256) {
        int2 e = binned[i];
        int pos = atomicAdd(&lcur[e.y & 255], 1);
        epair[pos] = make_int2(e.x, __builtin_bit_cast(int, dinv[e.x]));
    }
}

// ---------------- fused weight convert: all W[K,N] fp32 -> Wt[N,K] bf16 -------------

__global__ __launch_bounds__(256) void k_wtall(const float* __restrict__ W1,
                                               const float* __restrict__ W2,
                                               const float* __restrict__ W3,
                                               const float* __restrict__ Wf,
                                               const float* __restrict__ Wh1,
                                               const float* __restrict__ Wh2,
                                               const float* __restrict__ Wh3,
                                               unsigned short* __restrict__ Wt1,
                                               unsigned short* __restrict__ Wt2,
                                               unsigned short* __restrict__ Wt3,
                                               unsigned short* __restrict__ Wtf,
                                               unsigned short* __restrict__ Wth1,
                                               unsigned short* __restrict__ Wth2,
                                               unsigned short* __restrict__ Wth3) {
    int i = blockIdx.x * 256 + threadIdx.x;
    const float* W; unsigned short* Wt; int K, N, idx;
    if (i < 16384)       { W = W1;  Wt = Wt1;  K = 128; N = 128; idx = i; }
    else if (i < 32768)  { W = W2;  Wt = Wt2;  K = 128; N = 128; idx = i - 16384; }
    else if (i < 49152)  { W = W3;  Wt = Wt3;  K = 128; N = 128; idx = i - 32768; }
    else if (i < 65536)  { W = Wf;  Wt = Wtf;  K = 128; N = 128; idx = i - 49152; }
    else if (i < 180224) { W = Wh1; Wt = Wth1; K = 448; N = 256; idx = i - 65536; }
    else if (i < 212992) { W = Wh2; Wt = Wth2; K = 256; N = 128; idx = i - 180224; }
    else if (i < 221184) { W = Wh3; Wt = Wth3; K = 128; N = 64;  idx = i - 212992; }
    else return;
    int k = idx / N, n = idx % N;
    Wt[(size_t)n * K + k] = bf16_rn(W[idx]);
}

// ---------------- bf16 MFMA GEMM: C[M,Ntot] = A[M,K] @ Wt^T (+bias)(+relu) ---------

template <int K, int BN, int TN, int ACT, int OUTB, int AF32>
__global__ __launch_bounds__(256) void k_mfma(const void* __restrict__ Ap,
                                              const unsigned short* __restrict__ Wt,
                                              const float* __restrict__ bias,
                                              void* __restrict__ Cp,
                                              int M, int Ntot) {
    constexpr int TM = 4;
    __shared__ unsigned short Al[128][72];
    __shared__ unsigned short Bl[BN][72];
    const int t = threadIdx.x;
    const int lane = t & 63, wave = t >> 6;
    const int ln = lane & 15, q8 = (lane >> 4) * 8;
    const int row0 = blockIdx.x * 128;
    const int col0 = blockIdx.y * BN;
    const int wm0 = (wave >> 1) * 64;
    const int wn0 = (wave & 1) * (TN * 16);
    f32x4 acc[TM][TN];
#pragma unroll
    for (int i = 0; i < TM; i++)
#pragma unroll
        for (int j = 0; j < TN; j++) acc[i][j] = (f32x4){0.f, 0.f, 0.f, 0.f};

    for (int k0 = 0; k0 < K; k0 += 64) {
#pragma unroll
        for (int it = 0; it < 4; it++) {
            int c = it * 256 + t;
            int r = c >> 3, cc = (c & 7) * 8;
            int grow = row0 + r;
            if (AF32) {
                const float* A = (const float*)Ap;
                union { unsigned short u[8]; short8 v; } tm8;
                if (grow < M) {
                    float4 v0 = *(const float4*)&A[(size_t)grow * K + k0 + cc];
                    float4 v1 = *(const float4*)&A[(size_t)grow * K + k0 + cc + 4];
                    tm8.u[0] = bf16_rn(v0.x); tm8.u[1] = bf16_rn(v0.y);
                    tm8.u[2] = bf16_rn(v0.z); tm8.u[3] = bf16_rn(v0.w);
                    tm8.u[4] = bf16_rn(v1.x); tm8.u[5] = bf16_rn(v1.y);
                    tm8.u[6] = bf16_rn(v1.z); tm8.u[7] = bf16_rn(v1.w);
                } else {
                    tm8.v = (short8){0, 0, 0, 0, 0, 0, 0, 0};
                }
                *(short8*)&Al[r][cc] = tm8.v;
            } else {
                const unsigned short* A = (const unsigned short*)Ap;
                short8 v = (short8){0, 0, 0, 0, 0, 0, 0, 0};
                if (grow < M) v = *(const short8*)&A[(size_t)grow * K + k0 + cc];
                *(short8*)&Al[r][cc] = v;
            }
        }
#pragma unroll
        for (int it = 0; it < BN / 32; it++) {
            int c = it * 256 + t;
            int r = c >> 3, cc = (c & 7) * 8;
            *(short8*)&Bl[r][cc] = *(const short8*)&Wt[(size_t)(col0 + r) * K + k0 + cc];
        }
        __syncthreads();
#pragma unroll
        for (int ks = 0; ks < 64; ks += 32) {
            short8 af[TM], bfr[TN];
#pragma unroll
            for (int i = 0; i < TM; i++)
                af[i] = *(const short8*)&Al[wm0 + i * 16 + ln][ks + q8];
#pragma unroll
            for (int j = 0; j < TN; j++)
                bfr[j] = *(const short8*)&Bl[wn0 + j * 16 + ln][ks + q8];
#pragma unroll
            for (int i = 0; i < TM; i++)
#pragma unroll
                for (int j = 0; j < TN; j++)
                    acc[i][j] = __builtin_amdgcn_mfma_f32_16x16x32_bf16(af[i], bfr[j], acc[i][j], 0, 0, 0);
        }
        __syncthreads();
    }
    const int qr = (lane >> 4) * 4;
#pragma unroll
    for (int i = 0; i < TM; i++) {
#pragma unroll
        for (int j = 0; j < TN; j++) {
            int col = col0 + wn0 + j * 16 + ln;
            float bv = bias ? bias[col] : 0.f;
#pragma unroll
            for (int r = 0; r < 4; r++) {
                int row = row0 + wm0 + i * 16 + qr + r;
                if (row < M) {
                    float v = acc[i][j][r] + bv;
                    if (ACT) v = fmaxf(v, 0.f);
                    if (OUTB) ((unsigned short*)Cp)[(size_t)row * Ntot + col] = bf16_rn(v);
                    else      ((float*)Cp)[(size_t)row * Ntot + col] = v;
                }
            }
        }
    }
}

// ---------------- temporal GEMM with fused embedding gather: K=128 -> N=128 ---------

__global__ __launch_bounds__(256) void k_tempm(const int* __restrict__ day_ids,
                                               const int* __restrict__ time_ids,
                                               const float* __restrict__ day_table,
                                               const float* __restrict__ time_table,
                                               const unsigned short* __restrict__ Wt,
                                               const float* __restrict__ bias,
                                               unsigned short* __restrict__ Cout) {
    constexpr int TM = 4, TN = 4;
    __shared__ unsigned short Al[128][72];
    __shared__ unsigned short Bl[128][72];
    __shared__ int dayl[128], timel[128];
    const int t = threadIdx.x;
    const int lane = t & 63, wave = t >> 6;
    const int ln = lane & 15, q8 = (lane >> 4) * 8;
    const int row0 = blockIdx.x * 128;
    const int wm0 = (wave >> 1) * 64, wn0 = (wave & 1) * 64;
    if (t < 128) { dayl[t] = day_ids[row0 + t]; timel[t] = time_ids[row0 + t]; }
    f32x4 acc[TM][TN];
#pragma unroll
    for (int i = 0; i < TM; i++)
#pragma unroll
        for (int j = 0; j < TN; j++) acc[i][j] = (f32x4){0.f, 0.f, 0.f, 0.f};
    __syncthreads();

    for (int k0 = 0; k0 < 128; k0 += 64) {
        const float* tab = k0 ? time_table : day_table;
        const int*   ids = k0 ? timel : dayl;
#pragma unroll
        for (int it = 0; it < 4; it++) {
            int c = it * 256 + t;
            int r = c >> 3, cc = (c & 7) * 8;
            const float* p = &tab[(size_t)ids[r] * 64 + cc];
            float4 v0 = *(const float4*)p;
            float4 v1 = *(const float4*)(p + 4);
            union { unsigned short u[8]; short8 v; } tm8;
            tm8.u[0] = bf16_rn(v0.x); tm8.u[1] = bf16_rn(v0.y);
            tm8.u[2] = bf16_rn(v0.z); tm8.u[3] = bf16_rn(v0.w);
            tm8.u[4] = bf16_rn(v1.x); tm8.u[5] = bf16_rn(v1.y);
            tm8.u[6] = bf16_rn(v1.z); tm8.u[7] = bf16_rn(v1.w);
            *(short8*)&Al[r][cc] = tm8.v;
        }
#pragma unroll
        for (int it = 0; it < 4; it++) {
            int c = it * 256 + t;
            int r = c >> 3, cc = (c & 7) * 8;
            *(short8*)&Bl[r][cc] = *(const short8*)&Wt[(size_t)r * 128 + k0 + cc];
        }
        __syncthreads();
#pragma unroll
        for (int ks = 0; ks < 64; ks += 32) {
            short8 af[TM], bfr[TN];
#pragma unroll
            for (int i = 0; i < TM; i++)
                af[i] = *(const short8*)&Al[wm0 + i * 16 + ln][ks + q8];
#pragma unroll
            for (int j = 0; j < TN; j++)
                bfr[j] = *(const short8*)&Bl[wn0 + j * 16 + ln][ks + q8];
#pragma unroll
            for (int i = 0; i < TM; i++)
#pragma unroll
                for (int j = 0; j < TN; j++)
                    acc[i][j] = __builtin_amdgcn_mfma_f32_16x16x32_bf16(af[i], bfr[j], acc[i][j], 0, 0, 0);
        }
        __syncthreads();
    }
    const int qr = (lane >> 4) * 4;
#pragma unroll
    for (int i = 0; i < TM; i++) {
#pragma unroll
        for (int j = 0; j < TN; j++) {
            int col = wn0 + j * 16 + ln;
            float bv = bias[col];
#pragma unroll
            for (int r = 0; r < 4; r++) {
                int row = row0 + wm0 + i * 16 + qr + r;
                float v = fmaxf(acc[i][j][r] + bv, 0.f);
                Cout[(size_t)row * 128 + col] = bf16_rn(v);
            }
        }
    }
}

// ---------------- head1: fused gather A (h[o]|h[d]|temporal|mode), K=448, N=256 -----

__global__ __launch_bounds__(256) void k_head1m(const unsigned short* __restrict__ hb,
                                                const unsigned short* __restrict__ tmp,
                                                const int* __restrict__ orig,
                                                const int* __restrict__ dest,
                                                const int* __restrict__ mode_ids,
                                                const float* __restrict__ mode_table,
                                                const unsigned short* __restrict__ Wt,
                                                const float* __restrict__ bias,
                                                unsigned short* __restrict__ z1) {
    constexpr int TM = 4, TN = 4;
    __shared__ unsigned short Al[128][72];
    __shared__ unsigned short Bl[128][72];
    __shared__ int io[128], idd[128], im[128];
    const int t = threadIdx.x;
    const int lane = t & 63, wave = t >> 6;
    const int ln = lane & 15, q8 = (lane >> 4) * 8;
    const int row0 = blockIdx.x * 128;
    const int col0 = blockIdx.y * 128;
    const int wm0 = (wave >> 1) * 64, wn0 = (wave & 1) * 64;
    if (t < 128) {
        io[t] = orig[row0 + t];
        idd[t] = dest[row0 + t];
        im[t] = mode_ids[row0 + t];
    }
    f32x4 acc[TM][TN];
#pragma unroll
    for (int i = 0; i < TM; i++)
#pragma unroll
        for (int j = 0; j < TN; j++) acc[i][j] = (f32x4){0.f, 0.f, 0.f, 0.f};
    __syncthreads();

    for (int k0 = 0; k0 < 448; k0 += 64) {
#pragma unroll
        for (int it = 0; it < 4; it++) {
            int c = it * 256 + t;
            int r = c >> 3, cc = (c & 7) * 8;
            int gk = k0 + cc;
            short8 v;
            if (gk < 128)       v = *(const short8*)&hb[(size_t)io[r] * 128 + gk];
            else if (gk < 256)  v = *(const short8*)&hb[(size_t)idd[r] * 128 + (gk - 128)];
            else if (gk < 384)  v = *(const short8*)&tmp[(size_t)(row0 + r) * 128 + (gk - 256)];
            else {
                const float* mp = &mode_table[(size_t)im[r] * 64 + (gk - 384)];
                float4 v0 = *(const float4*)mp;
                float4 v1 = *(const float4*)(mp + 4);
                union { unsigned short u[8]; short8 v; } tm8;
                tm8.u[0] = bf16_rn(v0.x); tm8.u[1] = bf16_rn(v0.y);
                tm8.u[2] = bf16_rn(v0.z); tm8.u[3] = bf16_rn(v0.w);
                tm8.u[4] = bf16_rn(v1.x); tm8.u[5] = bf16_rn(v1.y);
                tm8.u[6] = bf16_rn(v1.z); tm8.u[7] = bf16_rn(v1.w);
                v = tm8.v;
            }
            *(short8*)&Al[r][cc] = v;
        }
#pragma unroll
        for (int it = 0; it < 4; it++) {
            int c = it * 256 + t;
            int r = c >> 3, cc = (c & 7) * 8;
            *(short8*)&Bl[r][cc] = *(const short8*)&Wt[(size_t)(col0 + r) * 448 + k0 + cc];
        }
        __syncthreads();
#pragma unroll
        for (int ks = 0; ks < 64; ks += 32) {
            short8 af[TM], bfr[TN];
#pragma unroll
            for (int i = 0; i < TM; i++)
                af[i] = *(const short8*)&Al[wm0 + i * 16 + ln][ks + q8];
#pragma unroll
            for (int j = 0; j < TN; j++)
                bfr[j] = *(const short8*)&Bl[wn0 + j * 16 + ln][ks + q8];
#pragma unroll
            for (int i = 0; i < TM; i++)
#pragma unroll
                for (int j = 0; j < TN; j++)
                    acc[i][j] = __builtin_amdgcn_mfma_f32_16x16x32_bf16(af[i], bfr[j], acc[i][j], 0, 0, 0);
        }
        __syncthreads();
    }
    const int qr = (lane >> 4) * 4;
#pragma unroll
    for (int i = 0; i < TM; i++) {
#pragma unroll
        for (int j = 0; j < TN; j++) {
            int col = col0 + wn0 + j * 16 + ln;
            float bv = bias[col];
#pragma unroll
            for (int r = 0; r < 4; r++) {
                int row = row0 + wm0 + i * 16 + qr + r;
                float v = fmaxf(acc[i][j][r] + bv, 0.f);
                z1[(size_t)row * 256 + col] = bf16_rn(v);
            }
        }
    }
}

// ---------------- edge aggregation: 16 edges in flight, 16B/lane --------------------
// epair = (src, dinv[src]); out = relu(dinv_d*(sum + dinv_d*hw[d]) + bias)

__global__ __launch_bounds__(256) void k_agg(const unsigned short* __restrict__ hwb,
                                             const int2* __restrict__ epair,
                                             const int* __restrict__ offsets,
                                             const float* __restrict__ dinv,
                                             const float* __restrict__ bias,
                                             unsigned short* __restrict__ out) {
    int node = blockIdx.x * 4 + (threadIdx.x >> 6);
    int lane = threadIdx.x & 63;
    if (node >= NN) return;
    const int q = lane >> 4, l = lane & 15;
    float acc[8];
#pragma unroll
    for (int i = 0; i < 8; i++) acc[i] = 0.f;
    const int beg = offsets[node], end = offsets[node + 1];
    int e = beg;
    for (; e + 16 <= end; e += 16) {
        int2 p0 = epair[e + q];
        int2 p1 = epair[e + 4 + q];
        int2 p2 = epair[e + 8 + q];
        int2 p3 = epair[e + 12 + q];
        short8 v0 = *(const short8*)&hwb[(size_t)p0.x * 128 + l * 8];
        short8 v1 = *(const short8*)&hwb[(size_t)p1.x * 128 + l * 8];
        short8 v2 = *(const short8*)&hwb[(size_t)p2.x * 128 + l * 8];
        short8 v3 = *(const short8*)&hwb[(size_t)p3.x * 128 + l * 8];
        float c0 = __builtin_bit_cast(float, p0.y);
        float c1 = __builtin_bit_cast(float, p1.y);
        float c2 = __builtin_bit_cast(float, p2.y);
        float c3 = __builtin_bit_cast(float, p3.y);
#pragma unroll
        for (int i = 0; i < 8; i++) acc[i] = fmaf(bf2f((unsigned short)v0[i]), c0, acc[i]);
#pragma unroll
        for (int i = 0; i < 8; i++) acc[i] = fmaf(bf2f((unsigned short)v1[i]), c1, acc[i]);
#pragma unroll
        for (int i = 0; i < 8; i++) acc[i] = fmaf(bf2f((unsigned short)v2[i]), c2, acc[i]);
#pragma unroll
        for (int i = 0; i < 8; i++) acc[i] = fmaf(bf2f((unsigned short)v3[i]), c3, acc[i]);
    }
    for (; e < end; e += 4) {
        int ee = e + q;
        int ec = (ee < end) ? ee : (end - 1);
        int2 p = epair[ec];
        float c = (ee < end) ? __builtin_bit_cast(float, p.y) : 0.f;
        short8 v = *(const short8*)&hwb[(size_t)p.x * 128 + l * 8];
#pragma unroll
        for (int i = 0; i < 8; i++) acc[i] = fmaf(bf2f((unsigned short)v[i]), c, acc[i]);
    }
#pragma unroll
    for (int i = 0; i < 8; i++) {
        acc[i] += __shfl_xor(acc[i], 16);
        acc[i] += __shfl_xor(acc[i], 32);
    }
    if (q == 0) {
        float dd = dinv[node];
        short8 hs = *(const short8*)&hwb[(size_t)node * 128 + l * 8];
        float4 b0 = *(const float4*)&bias[l * 8];
        float4 b1 = *(const float4*)&bias[l * 8 + 4];
        float bb[8] = {b0.x, b0.y, b0.z, b0.w, b1.x, b1.y, b1.z, b1.w};
        union { unsigned short u[8]; short8 v; } o;
#pragma unroll
        for (int i = 0; i < 8; i++) {
            float s = fmaf(bf2f((unsigned short)hs[i]), dd, acc[i]);
            float v = fmaf(s, dd, bb[i]);
            o.u[i] = bf16_rn(fmaxf(v, 0.f));
        }
        *(short8*)&out[(size_t)node * 128 + l * 8] = o.v;
    }
}

// ---------------- head4: [B,64] @ [64,1] + sigmoid ----------------------------------

__global__ __launch_bounds__(256) void k_head4(const float* __restrict__ z3,
                                               const float* __restrict__ Wh4,
                                               const float* __restrict__ bh4,
                                               float* __restrict__ out) {
    __shared__ float w[64];
    int t = threadIdx.x;
    if (t < 64) w[t] = Wh4[t];
    __syncthreads();
    int r = blockIdx.x * 16 + (t / 16);
    int q = t % 16;
    const float4* z4 = (const float4*)z3;
    float4 v = z4[(size_t)r * 16 + q];
    float4 wq = *(const float4*)&w[4 * q];
    float s = v.x * wq.x + v.y * wq.y + v.z * wq.z + v.w * wq.w;
#pragma unroll
    for (int off = 1; off < 16; off <<= 1) s += __shfl_xor(s, off, 64);
    if (q == 0) out[r] = 1.0f / (1.0f + expf(-(s + bh4[0])));
}

// ---------------- launch ------------------------------------------------------------

extern "C" void kernel_launch(void* const* d_in, const int* in_sizes, int n_in,
                              void* d_out, int out_size, void* d_ws, size_t ws_size,
                              hipStream_t stream) {
    const float* x          = (const float*)d_in[0];
    const int*   eidx       = (const int*)d_in[1];
    const int*   esrc       = eidx;
    const int*   edst       = eidx + EE;
    const int*   origin     = (const int*)d_in[2];
    const int*   destid     = (const int*)d_in[3];
    const int*   day_ids    = (const int*)d_in[4];
    const int*   time_ids   = (const int*)d_in[5];
    const int*   mode_ids   = (const int*)d_in[6];
    const float* W1 = (const float*)d_in[7];   const float* b1 = (const float*)d_in[8];
    const float* W2 = (const float*)d_in[9];   const float* b2 = (const float*)d_in[10];
    const float* W3 = (const float*)d_in[11];  const float* b3 = (const float*)d_in[12];
    const float* day_table  = (const float*)d_in[13];
    const float* time_table = (const float*)d_in[14];
    const float* mode_table = (const float*)d_in[15];
    const float* Wf  = (const float*)d_in[16]; const float* bf  = (const float*)d_in[17];
    const float* Wh1 = (const float*)d_in[18]; const float* bh1 = (const float*)d_in[19];
    const float* Wh2 = (const float*)d_in[20]; const float* bh2 = (const float*)d_in[21];
    const float* Wh3 = (const float*)d_in[22]; const float* bh3 = (const float*)d_in[23];
    const float* Wh4 = (const float*)d_in[24]; const float* bh4 = (const float*)d_in[25];
    float* out = (float*)d_out;

    char* wsb = (char*)d_ws;
    size_t off = 0;
    auto alloc = [&](size_t bytes) -> char* {
        char* p = wsb + off;
        off = (off + bytes + 511) & ~(size_t)511;
        return p;
    };
    int*   bcnt    = (int*)alloc((NBK + 1) * 4);
    int*   bbase   = (int*)alloc((NBK + 1) * 4);
    int*   bcur    = (int*)alloc((NBK + 1) * 4);
    int*   offsets = (int*)alloc((size_t)(NN + 1) * 4);
    float* dinv    = (float*)alloc((size_t)NN * 4);
    int2*  binned  = (int2*)alloc((size_t)EE * 8);
    int2*  epair   = (int2*)alloc((size_t)EE * 8);
    unsigned short* Wt1  = (unsigned short*)alloc(128 * 128 * 2);
    unsigned short* Wt2  = (unsigned short*)alloc(128 * 128 * 2);
    unsigned short* Wt3  = (unsigned short*)alloc(128 * 128 * 2);
    unsigned short* Wtf  = (unsigned short*)alloc(128 * 128 * 2);
    unsigned short* Wth1 = (unsigned short*)alloc(256 * 448 * 2);
    unsigned short* Wth2 = (unsigned short*)alloc(128 * 256 * 2);
    unsigned short* Wth3 = (unsigned short*)alloc(64 * 128 * 2);
    unsigned short* bufHW = (unsigned short*)alloc((size_t)NN * 128 * 2);
    unsigned short* bufH  = (unsigned short*)alloc((size_t)NN * 128 * 2);
    unsigned short* temporal = (unsigned short*)alloc((size_t)BQ * 128 * 2);
    unsigned short* z1 = (unsigned short*)alloc((size_t)BQ * 256 * 2);
    float* z3 = (float*)alloc((size_t)BQ * 64 * 4);
    unsigned short* z2 = temporal;  // temporal dead after head1m

    hipMemsetAsync(bcnt, 0, (NBK + 1) * 4, stream);
    k_bcount<<<256, 256, 0, stream>>>(edst, bcnt);
    k_bscan<<<1, 512, 0, stream>>>(bcnt, bbase, bcur);
    k_bin<<<256, 256, 0, stream>>>(esrc, edst, bcur, binned);
    k_boff<<<NBK, 256, 0, stream>>>(binned, bbase, offsets, dinv);
    k_place<<<NBK, 256, 0, stream>>>(binned, bbase, offsets, dinv, epair);

    k_wtall<<<(221184 + 255) / 256, 256, 0, stream>>>(W1, W2, W3, Wf, Wh1, Wh2, Wh3,
                                                      Wt1, Wt2, Wt3, Wtf, Wth1, Wth2, Wth3);

    const int GB = (NN + 127) / 128;  // 782
    k_mfma<128, 128, 4, 0, 1, 1><<<dim3(GB, 1), 256, 0, stream>>>(x, Wt1, nullptr, bufHW, NN, 128);
    k_agg<<<(NN + 3) / 4, 256, 0, stream>>>(bufHW, epair, offsets, dinv, b1, bufH);
    k_mfma<128, 128, 4, 0, 1, 0><<<dim3(GB, 1), 256, 0, stream>>>(bufH, Wt2, nullptr, bufHW, NN, 128);
    k_agg<<<(NN + 3) / 4, 256, 0, stream>>>(bufHW, epair, offsets, dinv, b2, bufH);
    k_mfma<128, 128, 4, 0, 1, 0><<<dim3(GB, 1), 256, 0, stream>>>(bufH, Wt3, nullptr, bufHW, NN, 128);
    k_agg<<<(NN + 3) / 4, 256, 0, stream>>>(bufHW, epair, offsets, dinv, b3, bufH);
    // final h = bufH (bf16)

    k_tempm<<<BQ / 128, 256, 0, stream>>>(day_ids, time_ids, day_table, time_table,
                                          Wtf, bf, temporal);
    k_head1m<<<dim3(BQ / 128, 2), 256, 0, stream>>>(bufH, temporal, origin, destid, mode_ids,
                                                    mode_table, Wth1, bh1, z1);
    k_mfma<256, 128, 4, 1, 1, 0><<<dim3(BQ / 128, 1), 256, 0, stream>>>(z1, Wth2, bh2, z2, BQ, 128);
    k_mfma<128, 64, 2, 1, 0, 0><<<dim3(BQ / 128, 1), 256, 0, stream>>>(z2, Wth3, bh3, z3, BQ, 64);
    k_head4<<<BQ / 16, 256, 0, stream>>>(z3, Wh4, bh4, out);
}

// Round 5
// 575.607 us; speedup vs baseline: 2.4326x; 1.0128x over previous
//
#include <hip/hip_runtime.h>

#define NN 100000   // nodes
#define EE 1600000  // edges
#define BQ 65536    // queries
#define NBK 391     // node buckets of 256 (ceil(NN/256))
#define ECH 6250    // edges per binning block (EE/256)

typedef __attribute__((ext_vector_type(8))) short short8;
typedef __attribute__((ext_vector_type(4))) float f32x4;

__device__ __forceinline__ unsigned short bf16_rn(float f) {
    unsigned u = __builtin_bit_cast(unsigned, f);
    u += 0x7fff + ((u >> 16) & 1);
    return (unsigned short)(u >> 16);
}
__device__ __forceinline__ float bf2f(unsigned short h) {
    unsigned u = ((unsigned)h) << 16;
    return __builtin_bit_cast(float, u);
}

// ---------------- bucket count: LDS hist of dst>>8 ----------------------------------

__global__ __launch_bounds__(256) void k_bcount(const int* __restrict__ dst,
                                                int* __restrict__ bcnt) {
    __shared__ int h[NBK];
    int t = threadIdx.x, b = blockIdx.x;
    for (int j = t; j < NBK; j += 256) h[j] = 0;
    __syncthreads();
    int lo = b * ECH, hi = lo + ECH;
    for (int i = lo + t; i < hi; i += 256) atomicAdd(&h[dst[i] >> 8], 1);
    __syncthreads();
    for (int j = t; j < NBK; j += 256)
        if (h[j]) atomicAdd(&bcnt[j], h[j]);
}

// ---------------- bucket scan: bbase = excl scan, init cursor -----------------------

__global__ __launch_bounds__(512) void k_bscan(const int* __restrict__ bcnt,
                                               int* __restrict__ bbase,
                                               int* __restrict__ bcur) {
    __shared__ int sd[512];
    int t = threadIdx.x;
    int v = (t < NBK) ? bcnt[t] : 0;
    sd[t] = v;
    __syncthreads();
    for (int o = 1; o < 512; o <<= 1) {
        int x = (t >= o) ? sd[t - o] : 0;
        __syncthreads();
        sd[t] += x;
        __syncthreads();
    }
    if (t < NBK) { int e = sd[t] - v; bbase[t] = e; bcur[t] = e; }
    if (t == 0) bbase[NBK] = EE;
}

// ---------------- binning: multisplit into 391 buckets, run-coalesced writes --------

__global__ __launch_bounds__(256) void k_bin(const int* __restrict__ src,
                                             const int* __restrict__ dst,
                                             int* __restrict__ bcur,
                                             int2* __restrict__ binned) {
    __shared__ int h[NBK];
    __shared__ int cur[NBK];
    int t = threadIdx.x, b = blockIdx.x;
    for (int j = t; j < NBK; j += 256) { h[j] = 0; cur[j] = 0; }
    __syncthreads();
    int lo = b * ECH, hi = lo + ECH;
    for (int i = lo + t; i < hi; i += 256) atomicAdd(&h[dst[i] >> 8], 1);
    __syncthreads();
    for (int j = t; j < NBK; j += 256)
        if (h[j]) h[j] = atomicAdd(&bcur[j], h[j]);
    __syncthreads();
    for (int i = lo + t; i < hi; i += 256) {
        int d = dst[i], bk = d >> 8;
        int pos = h[bk] + atomicAdd(&cur[bk], 1);
        binned[pos] = make_int2(src[i], d);
    }
}

// ---------------- per-bucket: node offsets + dinv -----------------------------------

__global__ __launch_bounds__(256) void k_boff(const int2* __restrict__ binned,
                                              const int* __restrict__ bbase,
                                              int* __restrict__ offsets,
                                              float* __restrict__ dinv) {
    __shared__ int lh[256];
    __shared__ int sd[256];
    int t = threadIdx.x, b = blockIdx.x;
    lh[t] = 0;
    __syncthreads();
    int lo = bbase[b], hi = bbase[b + 1];
    for (int i = lo + t; i < hi; i += 256) atomicAdd(&lh[binned[i].y & 255], 1);
    __syncthreads();
    int v = lh[t];
    sd[t] = v;
    __syncthreads();
    for (int o = 1; o < 256; o <<= 1) {
        int x = (t >= o) ? sd[t - o] : 0;
        __syncthreads();
        sd[t] += x;
        __syncthreads();
    }
    int node = (b << 8) + t;
    if (node < NN) {
        offsets[node] = lo + (sd[t] - v);
        dinv[node] = rsqrtf((float)v + 1.0f);
    }
    if (b == NBK - 1 && t == 0) offsets[NN] = EE;
}

// ---------------- placement: bucket-local windows, merged writes --------------------

__global__ __launch_bounds__(256) void k_place(const int2* __restrict__ binned,
                                               const int* __restrict__ bbase,
                                               const int* __restrict__ offsets,
                                               const float* __restrict__ dinv,
                                               int2* __restrict__ epair) {
    __shared__ int lcur[256];
    int t = threadIdx.x, b = blockIdx.x;
    int node = (b << 8) + t;
    lcur[t] = (node < NN) ? offsets[node] : 0;
    __syncthreads();
    int lo = bbase[b], hi = bbase[b + 1];
    for (int i = lo + t; i < hi; i += 256) {
        int2 e = binned[i];
        int pos = atomicAdd(&lcur[e.y & 255], 1);
        epair[pos] = make_int2(e.x, __builtin_bit_cast(int, dinv[e.x]));
    }
}

// ---------------- fused weight convert: all W[K,N] fp32 -> Wt[N,K] bf16 -------------

__global__ __launch_bounds__(256) void k_wtall(const float* __restrict__ W1,
                                               const float* __restrict__ W2,
                                               const float* __restrict__ W3,
                                               const float* __restrict__ Wf,
                                               const float* __restrict__ Wh1,
                                               const float* __restrict__ Wh2,
                                               const float* __restrict__ Wh3,
                                               unsigned short* __restrict__ Wt1,
                                               unsigned short* __restrict__ Wt2,
                                               unsigned short* __restrict__ Wt3,
                                               unsigned short* __restrict__ Wtf,
                                               unsigned short* __restrict__ Wth1,
                                               unsigned short* __restrict__ Wth2,
                                               unsigned short* __restrict__ Wth3) {
    int i = blockIdx.x * 256 + threadIdx.x;
    const float* W; unsigned short* Wt; int K, N, idx;
    if (i < 16384)       { W = W1;  Wt = Wt1;  K = 128; N = 128; idx = i; }
    else if (i < 32768)  { W = W2;  Wt = Wt2;  K = 128; N = 128; idx = i - 16384; }
    else if (i < 49152)  { W = W3;  Wt = Wt3;  K = 128; N = 128; idx = i - 32768; }
    else if (i < 65536)  { W = Wf;  Wt = Wtf;  K = 128; N = 128; idx = i - 49152; }
    else if (i < 180224) { W = Wh1; Wt = Wth1; K = 448; N = 256; idx = i - 65536; }
    else if (i < 212992) { W = Wh2; Wt = Wth2; K = 256; N = 128; idx = i - 180224; }
    else if (i < 221184) { W = Wh3; Wt = Wth3; K = 128; N = 64;  idx = i - 212992; }
    else return;
    int k = idx / N, n = idx % N;
    Wt[(size_t)n * K + k] = bf16_rn(W[idx]);
}

// ---------------- bf16 MFMA GEMM: C[M,Ntot] = A[M,K] @ Wt^T (+bias)(+relu) ---------

template <int K, int BN, int TN, int ACT, int OUTB, int AF32>
__global__ __launch_bounds__(256) void k_mfma(const void* __restrict__ Ap,
                                              const unsigned short* __restrict__ Wt,
                                              const float* __restrict__ bias,
                                              void* __restrict__ Cp,
                                              int M, int Ntot) {
    constexpr int TM = 4;
    __shared__ unsigned short Al[128][72];
    __shared__ unsigned short Bl[BN][72];
    const int t = threadIdx.x;
    const int lane = t & 63, wave = t >> 6;
    const int ln = lane & 15, q8 = (lane >> 4) * 8;
    const int row0 = blockIdx.x * 128;
    const int col0 = blockIdx.y * BN;
    const int wm0 = (wave >> 1) * 64;
    const int wn0 = (wave & 1) * (TN * 16);
    f32x4 acc[TM][TN];
#pragma unroll
    for (int i = 0; i < TM; i++)
#pragma unroll
        for (int j = 0; j < TN; j++) acc[i][j] = (f32x4){0.f, 0.f, 0.f, 0.f};

    for (int k0 = 0; k0 < K; k0 += 64) {
#pragma unroll
        for (int it = 0; it < 4; it++) {
            int c = it * 256 + t;
            int r = c >> 3, cc = (c & 7) * 8;
            int grow = row0 + r;
            if (AF32) {
                const float* A = (const float*)Ap;
                union { unsigned short u[8]; short8 v; } tm8;
                if (grow < M) {
                    float4 v0 = *(const float4*)&A[(size_t)grow * K + k0 + cc];
                    float4 v1 = *(const float4*)&A[(size_t)grow * K + k0 + cc + 4];
                    tm8.u[0] = bf16_rn(v0.x); tm8.u[1] = bf16_rn(v0.y);
                    tm8.u[2] = bf16_rn(v0.z); tm8.u[3] = bf16_rn(v0.w);
                    tm8.u[4] = bf16_rn(v1.x); tm8.u[5] = bf16_rn(v1.y);
                    tm8.u[6] = bf16_rn(v1.z); tm8.u[7] = bf16_rn(v1.w);
                } else {
                    tm8.v = (short8){0, 0, 0, 0, 0, 0, 0, 0};
                }
                *(short8*)&Al[r][cc] = tm8.v;
            } else {
                const unsigned short* A = (const unsigned short*)Ap;
                short8 v = (short8){0, 0, 0, 0, 0, 0, 0, 0};
                if (grow < M) v = *(const short8*)&A[(size_t)grow * K + k0 + cc];
                *(short8*)&Al[r][cc] = v;
            }
        }
#pragma unroll
        for (int it = 0; it < BN / 32; it++) {
            int c = it * 256 + t;
            int r = c >> 3, cc = (c & 7) * 8;
            *(short8*)&Bl[r][cc] = *(const short8*)&Wt[(size_t)(col0 + r) * K + k0 + cc];
        }
        __syncthreads();
#pragma unroll
        for (int ks = 0; ks < 64; ks += 32) {
            short8 af[TM], bfr[TN];
#pragma unroll
            for (int i = 0; i < TM; i++)
                af[i] = *(const short8*)&Al[wm0 + i * 16 + ln][ks + q8];
#pragma unroll
            for (int j = 0; j < TN; j++)
                bfr[j] = *(const short8*)&Bl[wn0 + j * 16 + ln][ks + q8];
#pragma unroll
            for (int i = 0; i < TM; i++)
#pragma unroll
                for (int j = 0; j < TN; j++)
                    acc[i][j] = __builtin_amdgcn_mfma_f32_16x16x32_bf16(af[i], bfr[j], acc[i][j], 0, 0, 0);
        }
        __syncthreads();
    }
    const int qr = (lane >> 4) * 4;
#pragma unroll
    for (int i = 0; i < TM; i++) {
#pragma unroll
        for (int j = 0; j < TN; j++) {
            int col = col0 + wn0 + j * 16 + ln;
            float bv = bias ? bias[col] : 0.f;
#pragma unroll
            for (int r = 0; r < 4; r++) {
                int row = row0 + wm0 + i * 16 + qr + r;
                if (row < M) {
                    float v = acc[i][j][r] + bv;
                    if (ACT) v = fmaxf(v, 0.f);
                    if (OUTB) ((unsigned short*)Cp)[(size_t)row * Ntot + col] = bf16_rn(v);
                    else      ((float*)Cp)[(size_t)row * Ntot + col] = v;
                }
            }
        }
    }
}

// ---------------- temporal GEMM with fused embedding gather: K=128 -> N=128 ---------

__global__ __launch_bounds__(256) void k_tempm(const int* __restrict__ day_ids,
                                               const int* __restrict__ time_ids,
                                               const float* __restrict__ day_table,
                                               const float* __restrict__ time_table,
                                               const unsigned short* __restrict__ Wt,
                                               const float* __restrict__ bias,
                                               unsigned short* __restrict__ Cout) {
    constexpr int TM = 4, TN = 4;
    __shared__ unsigned short Al[128][72];
    __shared__ unsigned short Bl[128][72];
    __shared__ int dayl[128], timel[128];
    const int t = threadIdx.x;
    const int lane = t & 63, wave = t >> 6;
    const int ln = lane & 15, q8 = (lane >> 4) * 8;
    const int row0 = blockIdx.x * 128;
    const int wm0 = (wave >> 1) * 64, wn0 = (wave & 1) * 64;
    if (t < 128) { dayl[t] = day_ids[row0 + t]; timel[t] = time_ids[row0 + t]; }
    f32x4 acc[TM][TN];
#pragma unroll
    for (int i = 0; i < TM; i++)
#pragma unroll
        for (int j = 0; j < TN; j++) acc[i][j] = (f32x4){0.f, 0.f, 0.f, 0.f};
    __syncthreads();

    for (int k0 = 0; k0 < 128; k0 += 64) {
        const float* tab = k0 ? time_table : day_table;
        const int*   ids = k0 ? timel : dayl;
#pragma unroll
        for (int it = 0; it < 4; it++) {
            int c = it * 256 + t;
            int r = c >> 3, cc = (c & 7) * 8;
            const float* p = &tab[(size_t)ids[r] * 64 + cc];
            float4 v0 = *(const float4*)p;
            float4 v1 = *(const float4*)(p + 4);
            union { unsigned short u[8]; short8 v; } tm8;
            tm8.u[0] = bf16_rn(v0.x); tm8.u[1] = bf16_rn(v0.y);
            tm8.u[2] = bf16_rn(v0.z); tm8.u[3] = bf16_rn(v0.w);
            tm8.u[4] = bf16_rn(v1.x); tm8.u[5] = bf16_rn(v1.y);
            tm8.u[6] = bf16_rn(v1.z); tm8.u[7] = bf16_rn(v1.w);
            *(short8*)&Al[r][cc] = tm8.v;
        }
#pragma unroll
        for (int it = 0; it < 4; it++) {
            int c = it * 256 + t;
            int r = c >> 3, cc = (c & 7) * 8;
            *(short8*)&Bl[r][cc] = *(const short8*)&Wt[(size_t)r * 128 + k0 + cc];
        }
        __syncthreads();
#pragma unroll
        for (int ks = 0; ks < 64; ks += 32) {
            short8 af[TM], bfr[TN];
#pragma unroll
            for (int i = 0; i < TM; i++)
                af[i] = *(const short8*)&Al[wm0 + i * 16 + ln][ks + q8];
#pragma unroll
            for (int j = 0; j < TN; j++)
                bfr[j] = *(const short8*)&Bl[wn0 + j * 16 + ln][ks + q8];
#pragma unroll
            for (int i = 0; i < TM; i++)
#pragma unroll
                for (int j = 0; j < TN; j++)
                    acc[i][j] = __builtin_amdgcn_mfma_f32_16x16x32_bf16(af[i], bfr[j], acc[i][j], 0, 0, 0);
        }
        __syncthreads();
    }
    const int qr = (lane >> 4) * 4;
#pragma unroll
    for (int i = 0; i < TM; i++) {
#pragma unroll
        for (int j = 0; j < TN; j++) {
            int col = wn0 + j * 16 + ln;
            float bv = bias[col];
#pragma unroll
            for (int r = 0; r < 4; r++) {
                int row = row0 + wm0 + i * 16 + qr + r;
                float v = fmaxf(acc[i][j][r] + bv, 0.f);
                Cout[(size_t)row * 128 + col] = bf16_rn(v);
            }
        }
    }
}

// ---------------- head1: fused gather A (h[o]|h[d]|temporal|mode), K=448, N=256 -----

__global__ __launch_bounds__(256) void k_head1m(const unsigned short* __restrict__ hb,
                                                const unsigned short* __restrict__ tmp,
                                                const int* __restrict__ orig,
                                                const int* __restrict__ dest,
                                                const int* __restrict__ mode_ids,
                                                const float* __restrict__ mode_table,
                                                const unsigned short* __restrict__ Wt,
                                                const float* __restrict__ bias,
                                                unsigned short* __restrict__ z1) {
    constexpr int TM = 4, TN = 4;
    __shared__ unsigned short Al[128][72];
    __shared__ unsigned short Bl[128][72];
    __shared__ int io[128], idd[128], im[128];
    const int t = threadIdx.x;
    const int lane = t & 63, wave = t >> 6;
    const int ln = lane & 15, q8 = (lane >> 4) * 8;
    const int row0 = blockIdx.x * 128;
    const int col0 = blockIdx.y * 128;
    const int wm0 = (wave >> 1) * 64, wn0 = (wave & 1) * 64;
    if (t < 128) {
        io[t] = orig[row0 + t];
        idd[t] = dest[row0 + t];
        im[t] = mode_ids[row0 + t];
    }
    f32x4 acc[TM][TN];
#pragma unroll
    for (int i = 0; i < TM; i++)
#pragma unroll
        for (int j = 0; j < TN; j++) acc[i][j] = (f32x4){0.f, 0.f, 0.f, 0.f};
    __syncthreads();

    for (int k0 = 0; k0 < 448; k0 += 64) {
#pragma unroll
        for (int it = 0; it < 4; it++) {
            int c = it * 256 + t;
            int r = c >> 3, cc = (c & 7) * 8;
            int gk = k0 + cc;
            short8 v;
            if (gk < 128)       v = *(const short8*)&hb[(size_t)io[r] * 128 + gk];
            else if (gk < 256)  v = *(const short8*)&hb[(size_t)idd[r] * 128 + (gk - 128)];
            else if (gk < 384)  v = *(const short8*)&tmp[(size_t)(row0 + r) * 128 + (gk - 256)];
            else {
                const float* mp = &mode_table[(size_t)im[r] * 64 + (gk - 384)];
                float4 v0 = *(const float4*)mp;
                float4 v1 = *(const float4*)(mp + 4);
                union { unsigned short u[8]; short8 v; } tm8;
                tm8.u[0] = bf16_rn(v0.x); tm8.u[1] = bf16_rn(v0.y);
                tm8.u[2] = bf16_rn(v0.z); tm8.u[3] = bf16_rn(v0.w);
                tm8.u[4] = bf16_rn(v1.x); tm8.u[5] = bf16_rn(v1.y);
                tm8.u[6] = bf16_rn(v1.z); tm8.u[7] = bf16_rn(v1.w);
                v = tm8.v;
            }
            *(short8*)&Al[r][cc] = v;
        }
#pragma unroll
        for (int it = 0; it < 4; it++) {
            int c = it * 256 + t;
            int r = c >> 3, cc = (c & 7) * 8;
            *(short8*)&Bl[r][cc] = *(const short8*)&Wt[(size_t)(col0 + r) * 448 + k0 + cc];
        }
        __syncthreads();
#pragma unroll
        for (int ks = 0; ks < 64; ks += 32) {
            short8 af[TM], bfr[TN];
#pragma unroll
            for (int i = 0; i < TM; i++)
                af[i] = *(const short8*)&Al[wm0 + i * 16 + ln][ks + q8];
#pragma unroll
            for (int j = 0; j < TN; j++)
                bfr[j] = *(const short8*)&Bl[wn0 + j * 16 + ln][ks + q8];
#pragma unroll
            for (int i = 0; i < TM; i++)
#pragma unroll
                for (int j = 0; j < TN; j++)
                    acc[i][j] = __builtin_amdgcn_mfma_f32_16x16x32_bf16(af[i], bfr[j], acc[i][j], 0, 0, 0);
        }
        __syncthreads();
    }
    const int qr = (lane >> 4) * 4;
#pragma unroll
    for (int i = 0; i < TM; i++) {
#pragma unroll
        for (int j = 0; j < TN; j++) {
            int col = col0 + wn0 + j * 16 + ln;
            float bv = bias[col];
#pragma unroll
            for (int r = 0; r < 4; r++) {
                int row = row0 + wm0 + i * 16 + qr + r;
                float v = fmaxf(acc[i][j][r] + bv, 0.f);
                z1[(size_t)row * 256 + col] = bf16_rn(v);
            }
        }
    }
}

// ---------------- edge aggregation: wave = 4 nodes, quarter = 1 node, 8 edges deep --
// lane l (0..15) covers 16B of the 256B row; 32 gathers in flight per wave.
// epair = (src, dinv[src]); out = relu(dinv_d*(sum + dinv_d*hw[d]) + bias)

__global__ __launch_bounds__(256) void k_agg(const unsigned short* __restrict__ hwb,
                                             const int2* __restrict__ epair,
                                             const int* __restrict__ offsets,
                                             const float* __restrict__ dinv,
                                             const float* __restrict__ bias,
                                             unsigned short* __restrict__ out) {
    const int wid = blockIdx.x * 4 + (threadIdx.x >> 6);  // wave id
    const int lane = threadIdx.x & 63;
    const int q = lane >> 4, l = lane & 15;
    const int node = wid * 4 + q;
    if (node >= NN) return;
    float acc[8];
#pragma unroll
    for (int i = 0; i < 8; i++) acc[i] = 0.f;
    const int beg = offsets[node], end = offsets[node + 1];
    for (int e = beg; e < end; e += 8) {
        int2 p[8];
#pragma unroll
        for (int j = 0; j < 8; j++) {
            int ee = e + j;
            p[j] = epair[(ee < end) ? ee : (end - 1)];
        }
        short8 v[8];
#pragma unroll
        for (int j = 0; j < 8; j++)
            v[j] = *(const short8*)&hwb[(size_t)p[j].x * 128 + l * 8];
#pragma unroll
        for (int j = 0; j < 8; j++) {
            float c = (e + j < end) ? __builtin_bit_cast(float, p[j].y) : 0.f;
#pragma unroll
            for (int i = 0; i < 8; i++)
                acc[i] = fmaf(bf2f((unsigned short)v[j][i]), c, acc[i]);
        }
    }
    float dd = dinv[node];
    short8 hs = *(const short8*)&hwb[(size_t)node * 128 + l * 8];
    float4 b0 = *(const float4*)&bias[l * 8];
    float4 b1 = *(const float4*)&bias[l * 8 + 4];
    float bb[8] = {b0.x, b0.y, b0.z, b0.w, b1.x, b1.y, b1.z, b1.w};
    union { unsigned short u[8]; short8 v; } o;
#pragma unroll
    for (int i = 0; i < 8; i++) {
        float s = fmaf(bf2f((unsigned short)hs[i]), dd, acc[i]);
        float v = fmaf(s, dd, bb[i]);
        o.u[i] = bf16_rn(fmaxf(v, 0.f));
    }
    *(short8*)&out[(size_t)node * 128 + l * 8] = o.v;
}

// ---------------- head4: [B,64] @ [64,1] + sigmoid ----------------------------------

__global__ __launch_bounds__(256) void k_head4(const float* __restrict__ z3,
                                               const float* __restrict__ Wh4,
                                               const float* __restrict__ bh4,
                                               float* __restrict__ out) {
    __shared__ float w[64];
    int t = threadIdx.x;
    if (t < 64) w[t] = Wh4[t];
    __syncthreads();
    int r = blockIdx.x * 16 + (t / 16);
    int q = t % 16;
    const float4* z4 = (const float4*)z3;
    float4 v = z4[(size_t)r * 16 + q];
    float4 wq = *(const float4*)&w[4 * q];
    float s = v.x * wq.x + v.y * wq.y + v.z * wq.z + v.w * wq.w;
#pragma unroll
    for (int off = 1; off < 16; off <<= 1) s += __shfl_xor(s, off, 64);
    if (q == 0) out[r] = 1.0f / (1.0f + expf(-(s + bh4[0])));
}

// ---------------- launch ------------------------------------------------------------

extern "C" void kernel_launch(void* const* d_in, const int* in_sizes, int n_in,
                              void* d_out, int out_size, void* d_ws, size_t ws_size,
                              hipStream_t stream) {
    const float* x          = (const float*)d_in[0];
    const int*   eidx       = (const int*)d_in[1];
    const int*   esrc       = eidx;
    const int*   edst       = eidx + EE;
    const int*   origin     = (const int*)d_in[2];
    const int*   destid     = (const int*)d_in[3];
    const int*   day_ids    = (const int*)d_in[4];
    const int*   time_ids   = (const int*)d_in[5];
    const int*   mode_ids   = (const int*)d_in[6];
    const float* W1 = (const float*)d_in[7];   const float* b1 = (const float*)d_in[8];
    const float* W2 = (const float*)d_in[9];   const float* b2 = (const float*)d_in[10];
    const float* W3 = (const float*)d_in[11];  const float* b3 = (const float*)d_in[12];
    const float* day_table  = (const float*)d_in[13];
    const float* time_table = (const float*)d_in[14];
    const float* mode_table = (const float*)d_in[15];
    const float* Wf  = (const float*)d_in[16]; const float* bf  = (const float*)d_in[17];
    const float* Wh1 = (const float*)d_in[18]; const float* bh1 = (const float*)d_in[19];
    const float* Wh2 = (const float*)d_in[20]; const float* bh2 = (const float*)d_in[21];
    const float* Wh3 = (const float*)d_in[22]; const float* bh3 = (const float*)d_in[23];
    const float* Wh4 = (const float*)d_in[24]; const float* bh4 = (const float*)d_in[25];
    float* out = (float*)d_out;

    char* wsb = (char*)d_ws;
    size_t off = 0;
    auto alloc = [&](size_t bytes) -> char* {
        char* p = wsb + off;
        off = (off + bytes + 511) & ~(size_t)511;
        return p;
    };
    int*   bcnt    = (int*)alloc((NBK + 1) * 4);
    int*   bbase   = (int*)alloc((NBK + 1) * 4);
    int*   bcur    = (int*)alloc((NBK + 1) * 4);
    int*   offsets = (int*)alloc((size_t)(NN + 1) * 4);
    float* dinv    = (float*)alloc((size_t)NN * 4);
    int2*  binned  = (int2*)alloc((size_t)EE * 8);
    int2*  epair   = (int2*)alloc((size_t)EE * 8);
    unsigned short* Wt1  = (unsigned short*)alloc(128 * 128 * 2);
    unsigned short* Wt2  = (unsigned short*)alloc(128 * 128 * 2);
    unsigned short* Wt3  = (unsigned short*)alloc(128 * 128 * 2);
    unsigned short* Wtf  = (unsigned short*)alloc(128 * 128 * 2);
    unsigned short* Wth1 = (unsigned short*)alloc(256 * 448 * 2);
    unsigned short* Wth2 = (unsigned short*)alloc(128 * 256 * 2);
    unsigned short* Wth3 = (unsigned short*)alloc(64 * 128 * 2);
    unsigned short* bufHW = (unsigned short*)alloc((size_t)NN * 128 * 2);
    unsigned short* bufH  = (unsigned short*)alloc((size_t)NN * 128 * 2);
    unsigned short* temporal = (unsigned short*)alloc((size_t)BQ * 128 * 2);
    unsigned short* z1 = (unsigned short*)alloc((size_t)BQ * 256 * 2);
    float* z3 = (float*)alloc((size_t)BQ * 64 * 4);
    unsigned short* z2 = temporal;  // temporal dead after head1m

    hipMemsetAsync(bcnt, 0, (NBK + 1) * 4, stream);
    k_bcount<<<256, 256, 0, stream>>>(edst, bcnt);
    k_bscan<<<1, 512, 0, stream>>>(bcnt, bbase, bcur);
    k_bin<<<256, 256, 0, stream>>>(esrc, edst, bcur, binned);
    k_boff<<<NBK, 256, 0, stream>>>(binned, bbase, offsets, dinv);
    k_place<<<NBK, 256, 0, stream>>>(binned, bbase, offsets, dinv, epair);

    k_wtall<<<(221184 + 255) / 256, 256, 0, stream>>>(W1, W2, W3, Wf, Wh1, Wh2, Wh3,
                                                      Wt1, Wt2, Wt3, Wtf, Wth1, Wth2, Wth3);

    const int GB = (NN + 127) / 128;   // 782
    const int AB = (NN + 15) / 16;     // 6250 blocks, 16 nodes/block
    k_mfma<128, 128, 4, 0, 1, 1><<<dim3(GB, 1), 256, 0, stream>>>(x, Wt1, nullptr, bufHW, NN, 128);
    k_agg<<<AB, 256, 0, stream>>>(bufHW, epair, offsets, dinv, b1, bufH);
    k_mfma<128, 128, 4, 0, 1, 0><<<dim3(GB, 1), 256, 0, stream>>>(bufH, Wt2, nullptr, bufHW, NN, 128);
    k_agg<<<AB, 256, 0, stream>>>(bufHW, epair, offsets, dinv, b2, bufH);
    k_mfma<128, 128, 4, 0, 1, 0><<<dim3(GB, 1), 256, 0, stream>>>(bufH, Wt3, nullptr, bufHW, NN, 128);
    k_agg<<<AB, 256, 0, stream>>>(bufHW, epair, offsets, dinv, b3, bufH);
    // final h = bufH (bf16)

    k_tempm<<<BQ / 128, 256, 0, stream>>>(day_ids, time_ids, day_table, time_table,
                                          Wtf, bf, temporal);
    k_head1m<<<dim3(BQ / 128, 2), 256, 0, stream>>>(bufH, temporal, origin, destid, mode_ids,
                                                    mode_table, Wth1, bh1, z1);
    k_mfma<256, 128, 4, 1, 1, 0><<<dim3(BQ / 128, 1), 256, 0, stream>>>(z1, Wth2, bh2, z2, BQ, 128);
    k_mfma<128, 64, 2, 1, 0, 0><<<dim3(BQ / 128, 1), 256, 0, stream>>>(z2, Wth3, bh3, z3, BQ, 64);
    k_head4<<<BQ / 16, 256, 0, stream>>>(z3, Wh4, bh4, out);
}

// Round 6
// 505.584 us; speedup vs baseline: 2.7695x; 1.1385x over previous
//
#include <hip/hip_runtime.h>

#define NN 100000   // nodes
#define EE 1600000  // edges
#define BQ 65536    // queries
#define NBK 391     // node buckets of 256 (ceil(NN/256))
#define ECH 6250    // edges per binning block (EE/256)

typedef __attribute__((ext_vector_type(8))) short short8;
typedef __attribute__((ext_vector_type(4))) float f32x4;
typedef __attribute__((ext_vector_type(2))) float f32x2;

__device__ __forceinline__ unsigned short bf16_rn(float f) {
    unsigned u = __builtin_bit_cast(unsigned, f);
    u += 0x7fff + ((u >> 16) & 1);
    return (unsigned short)(u >> 16);
}
__device__ __forceinline__ float bf2f(unsigned short h) {
    unsigned u = ((unsigned)h) << 16;
    return __builtin_bit_cast(float, u);
}

// ---------------- fp8 e4m3 helpers (HW cvt with SW fallback) ------------------------

#if defined(__has_builtin)
#if __has_builtin(__builtin_amdgcn_cvt_pk_fp8_f32) && __has_builtin(__builtin_amdgcn_cvt_pk_f32_fp8)
#define HW_FP8 1
#endif
#endif
#ifndef HW_FP8
#define HW_FP8 0
#endif

__device__ __forceinline__ unsigned char sw_f32_to_e4m3(float f) {
    float a = fabsf(f);
    unsigned s = __builtin_bit_cast(unsigned, f) >> 31;
    if (!(a < 448.f)) return (unsigned char)((s << 7) | 0x7E);  // sat (incl inf/nan)
    if (a < 0.015625f) {                                        // subnormal (<2^-6)
        int q = (int)rintf(a * 512.0f);                         // lsb = 2^-9
        return (unsigned char)((s << 7) | q);
    }
    int e; float m = frexpf(a, &e);       // a = m*2^e, m in [0.5,1)
    int q = (int)rintf(m * 16.0f);        // in [8,16]
    int exp = e - 1 + 7;
    if (q == 16) { q = 8; exp++; }
    if (exp >= 16 || (exp == 15 && q == 15)) return (unsigned char)((s << 7) | 0x7E);
    return (unsigned char)((s << 7) | (exp << 3) | (q - 8));
}
__device__ __forceinline__ float sw_e4m3_to_f32(unsigned char v) {
    unsigned s = v >> 7, e = (v >> 3) & 15, m = v & 7;
    float r = e ? ldexpf((float)(8 + m), (int)e - 10) : ldexpf((float)m, -9);
    return s ? -r : r;
}

__device__ __forceinline__ unsigned char f32_to_e4m3b(float f) {
#if HW_FP8
    return (unsigned char)(__builtin_amdgcn_cvt_pk_fp8_f32(f, f, 0, false) & 0xFF);
#else
    return sw_f32_to_e4m3(f);
#endif
}
__device__ __forceinline__ void unpack4_e4m3(unsigned v, float* o) {
#if HW_FP8
    f32x2 lo = __builtin_amdgcn_cvt_pk_f32_fp8((int)v, false);
    f32x2 hi = __builtin_amdgcn_cvt_pk_f32_fp8((int)v, true);
    o[0] = lo[0]; o[1] = lo[1]; o[2] = hi[0]; o[3] = hi[1];
#else
    o[0] = sw_e4m3_to_f32(v & 0xFF);
    o[1] = sw_e4m3_to_f32((v >> 8) & 0xFF);
    o[2] = sw_e4m3_to_f32((v >> 16) & 0xFF);
    o[3] = sw_e4m3_to_f32((v >> 24) & 0xFF);
#endif
}

// ---------------- bucket count: LDS hist of dst>>8 ----------------------------------

__global__ __launch_bounds__(256) void k_bcount(const int* __restrict__ dst,
                                                int* __restrict__ bcnt) {
    __shared__ int h[NBK];
    int t = threadIdx.x, b = blockIdx.x;
    for (int j = t; j < NBK; j += 256) h[j] = 0;
    __syncthreads();
    int lo = b * ECH, hi = lo + ECH;
    for (int i = lo + t; i < hi; i += 256) atomicAdd(&h[dst[i] >> 8], 1);
    __syncthreads();
    for (int j = t; j < NBK; j += 256)
        if (h[j]) atomicAdd(&bcnt[j], h[j]);
}

// ---------------- bucket scan: bbase = excl scan, init cursor -----------------------

__global__ __launch_bounds__(512) void k_bscan(const int* __restrict__ bcnt,
                                               int* __restrict__ bbase,
                                               int* __restrict__ bcur) {
    __shared__ int sd[512];
    int t = threadIdx.x;
    int v = (t < NBK) ? bcnt[t] : 0;
    sd[t] = v;
    __syncthreads();
    for (int o = 1; o < 512; o <<= 1) {
        int x = (t >= o) ? sd[t - o] : 0;
        __syncthreads();
        sd[t] += x;
        __syncthreads();
    }
    if (t < NBK) { int e = sd[t] - v; bbase[t] = e; bcur[t] = e; }
    if (t == 0) bbase[NBK] = EE;
}

// ---------------- binning: multisplit into 391 buckets, run-coalesced writes --------

__global__ __launch_bounds__(256) void k_bin(const int* __restrict__ src,
                                             const int* __restrict__ dst,
                                             int* __restrict__ bcur,
                                             int2* __restrict__ binned) {
    __shared__ int h[NBK];
    __shared__ int cur[NBK];
    int t = threadIdx.x, b = blockIdx.x;
    for (int j = t; j < NBK; j += 256) { h[j] = 0; cur[j] = 0; }
    __syncthreads();
    int lo = b * ECH, hi = lo + ECH;
    for (int i = lo + t; i < hi; i += 256) atomicAdd(&h[dst[i] >> 8], 1);
    __syncthreads();
    for (int j = t; j < NBK; j += 256)
        if (h[j]) h[j] = atomicAdd(&bcur[j], h[j]);
    __syncthreads();
    for (int i = lo + t; i < hi; i += 256) {
        int d = dst[i], bk = d >> 8;
        int pos = h[bk] + atomicAdd(&cur[bk], 1);
        binned[pos] = make_int2(src[i], d);
    }
}

// ---------------- per-bucket: node offsets + dinv -----------------------------------

__global__ __launch_bounds__(256) void k_boff(const int2* __restrict__ binned,
                                              const int* __restrict__ bbase,
                                              int* __restrict__ offsets,
                                              float* __restrict__ dinv) {
    __shared__ int lh[256];
    __shared__ int sd[256];
    int t = threadIdx.x, b = blockIdx.x;
    lh[t] = 0;
    __syncthreads();
    int lo = bbase[b], hi = bbase[b + 1];
    for (int i = lo + t; i < hi; i += 256) atomicAdd(&lh[binned[i].y & 255], 1);
    __syncthreads();
    int v = lh[t];
    sd[t] = v;
    __syncthreads();
    for (int o = 1; o < 256; o <<= 1) {
        int x = (t >= o) ? sd[t - o] : 0;
        __syncthreads();
        sd[t] += x;
        __syncthreads();
    }
    int node = (b << 8) + t;
    if (node < NN) {
        offsets[node] = lo + (sd[t] - v);
        dinv[node] = rsqrtf((float)v + 1.0f);
    }
    if (b == NBK - 1 && t == 0) offsets[NN] = EE;
}

// ---------------- placement: bucket-local windows, merged writes --------------------

__global__ __launch_bounds__(256) void k_place(const int2* __restrict__ binned,
                                               const int* __restrict__ bbase,
                                               const int* __restrict__ offsets,
                                               const float* __restrict__ dinv,
                                               int2* __restrict__ epair) {
    __shared__ int lcur[256];
    int t = threadIdx.x, b = blockIdx.x;
    int node = (b << 8) + t;
    lcur[t] = (node < NN) ? offsets[node] : 0;
    __syncthreads();
    int lo = bbase[b], hi = bbase[b + 1];
    for (int i = lo + t; i < hi; i += 256) {
        int2 e = binned[i];
        int pos = atomicAdd(&lcur[e.y & 255], 1);
        epair[pos] = make_int2(e.x, __builtin_bit_cast(int, dinv[e.x]));
    }
}

// ---------------- fused weight convert: all W[K,N] fp32 -> Wt[N,K] bf16 -------------

__global__ __launch_bounds__(256) void k_wtall(const float* __restrict__ W1,
                                               const float* __restrict__ W2,
                                               const float* __restrict__ W3,
                                               const float* __restrict__ Wf,
                                               const float* __restrict__ Wh1,
                                               const float* __restrict__ Wh2,
                                               const float* __restrict__ Wh3,
                                               unsigned short* __restrict__ Wt1,
                                               unsigned short* __restrict__ Wt2,
                                               unsigned short* __restrict__ Wt3,
                                               unsigned short* __restrict__ Wtf,
                                               unsigned short* __restrict__ Wth1,
                                               unsigned short* __restrict__ Wth2,
                                               unsigned short* __restrict__ Wth3) {
    int i = blockIdx.x * 256 + threadIdx.x;
    const float* W; unsigned short* Wt; int K, N, idx;
    if (i < 16384)       { W = W1;  Wt = Wt1;  K = 128; N = 128; idx = i; }
    else if (i < 32768)  { W = W2;  Wt = Wt2;  K = 128; N = 128; idx = i - 16384; }
    else if (i < 49152)  { W = W3;  Wt = Wt3;  K = 128; N = 128; idx = i - 32768; }
    else if (i < 65536)  { W = Wf;  Wt = Wtf;  K = 128; N = 128; idx = i - 49152; }
    else if (i < 180224) { W = Wh1; Wt = Wth1; K = 448; N = 256; idx = i - 65536; }
    else if (i < 212992) { W = Wh2; Wt = Wth2; K = 256; N = 128; idx = i - 180224; }
    else if (i < 221184) { W = Wh3; Wt = Wth3; K = 128; N = 64;  idx = i - 212992; }
    else return;
    int k = idx / N, n = idx % N;
    Wt[(size_t)n * K + k] = bf16_rn(W[idx]);
}

// ---------------- bf16 MFMA GEMM: C = A @ Wt^T (+bias)(+relu) -----------------------
// OUTM: 0=f32, 1=bf16, 2=fp8-e4m3

template <int K, int BN, int TN, int ACT, int OUTM, int AF32>
__global__ __launch_bounds__(256) void k_mfma(const void* __restrict__ Ap,
                                              const unsigned short* __restrict__ Wt,
                                              const float* __restrict__ bias,
                                              void* __restrict__ Cp,
                                              int M, int Ntot) {
    constexpr int TM = 4;
    __shared__ unsigned short Al[128][72];
    __shared__ unsigned short Bl[BN][72];
    const int t = threadIdx.x;
    const int lane = t & 63, wave = t >> 6;
    const int ln = lane & 15, q8 = (lane >> 4) * 8;
    const int row0 = blockIdx.x * 128;
    const int col0 = blockIdx.y * BN;
    const int wm0 = (wave >> 1) * 64;
    const int wn0 = (wave & 1) * (TN * 16);
    f32x4 acc[TM][TN];
#pragma unroll
    for (int i = 0; i < TM; i++)
#pragma unroll
        for (int j = 0; j < TN; j++) acc[i][j] = (f32x4){0.f, 0.f, 0.f, 0.f};

    for (int k0 = 0; k0 < K; k0 += 64) {
#pragma unroll
        for (int it = 0; it < 4; it++) {
            int c = it * 256 + t;
            int r = c >> 3, cc = (c & 7) * 8;
            int grow = row0 + r;
            if (AF32) {
                const float* A = (const float*)Ap;
                union { unsigned short u[8]; short8 v; } tm8;
                if (grow < M) {
                    float4 v0 = *(const float4*)&A[(size_t)grow * K + k0 + cc];
                    float4 v1 = *(const float4*)&A[(size_t)grow * K + k0 + cc + 4];
                    tm8.u[0] = bf16_rn(v0.x); tm8.u[1] = bf16_rn(v0.y);
                    tm8.u[2] = bf16_rn(v0.z); tm8.u[3] = bf16_rn(v0.w);
                    tm8.u[4] = bf16_rn(v1.x); tm8.u[5] = bf16_rn(v1.y);
                    tm8.u[6] = bf16_rn(v1.z); tm8.u[7] = bf16_rn(v1.w);
                } else {
                    tm8.v = (short8){0, 0, 0, 0, 0, 0, 0, 0};
                }
                *(short8*)&Al[r][cc] = tm8.v;
            } else {
                const unsigned short* A = (const unsigned short*)Ap;
                short8 v = (short8){0, 0, 0, 0, 0, 0, 0, 0};
                if (grow < M) v = *(const short8*)&A[(size_t)grow * K + k0 + cc];
                *(short8*)&Al[r][cc] = v;
            }
        }
#pragma unroll
        for (int it = 0; it < BN / 32; it++) {
            int c = it * 256 + t;
            int r = c >> 3, cc = (c & 7) * 8;
            *(short8*)&Bl[r][cc] = *(const short8*)&Wt[(size_t)(col0 + r) * K + k0 + cc];
        }
        __syncthreads();
#pragma unroll
        for (int ks = 0; ks < 64; ks += 32) {
            short8 af[TM], bfr[TN];
#pragma unroll
            for (int i = 0; i < TM; i++)
                af[i] = *(const short8*)&Al[wm0 + i * 16 + ln][ks + q8];
#pragma unroll
            for (int j = 0; j < TN; j++)
                bfr[j] = *(const short8*)&Bl[wn0 + j * 16 + ln][ks + q8];
#pragma unroll
            for (int i = 0; i < TM; i++)
#pragma unroll
                for (int j = 0; j < TN; j++)
                    acc[i][j] = __builtin_amdgcn_mfma_f32_16x16x32_bf16(af[i], bfr[j], acc[i][j], 0, 0, 0);
        }
        __syncthreads();
    }
    const int qr = (lane >> 4) * 4;
#pragma unroll
    for (int i = 0; i < TM; i++) {
#pragma unroll
        for (int j = 0; j < TN; j++) {
            int col = col0 + wn0 + j * 16 + ln;
            float bv = bias ? bias[col] : 0.f;
#pragma unroll
            for (int r = 0; r < 4; r++) {
                int row = row0 + wm0 + i * 16 + qr + r;
                if (row < M) {
                    float v = acc[i][j][r] + bv;
                    if (ACT) v = fmaxf(v, 0.f);
                    if (OUTM == 1)      ((unsigned short*)Cp)[(size_t)row * Ntot + col] = bf16_rn(v);
                    else if (OUTM == 2) ((unsigned char*)Cp)[(size_t)row * Ntot + col] = f32_to_e4m3b(v);
                    else                ((float*)Cp)[(size_t)row * Ntot + col] = v;
                }
            }
        }
    }
}

// ---------------- temporal GEMM with fused embedding gather: K=128 -> N=128 ---------

__global__ __launch_bounds__(256) void k_tempm(const int* __restrict__ day_ids,
                                               const int* __restrict__ time_ids,
                                               const float* __restrict__ day_table,
                                               const float* __restrict__ time_table,
                                               const unsigned short* __restrict__ Wt,
                                               const float* __restrict__ bias,
                                               unsigned short* __restrict__ Cout) {
    constexpr int TM = 4, TN = 4;
    __shared__ unsigned short Al[128][72];
    __shared__ unsigned short Bl[128][72];
    __shared__ int dayl[128], timel[128];
    const int t = threadIdx.x;
    const int lane = t & 63, wave = t >> 6;
    const int ln = lane & 15, q8 = (lane >> 4) * 8;
    const int row0 = blockIdx.x * 128;
    const int wm0 = (wave >> 1) * 64, wn0 = (wave & 1) * 64;
    if (t < 128) { dayl[t] = day_ids[row0 + t]; timel[t] = time_ids[row0 + t]; }
    f32x4 acc[TM][TN];
#pragma unroll
    for (int i = 0; i < TM; i++)
#pragma unroll
        for (int j = 0; j < TN; j++) acc[i][j] = (f32x4){0.f, 0.f, 0.f, 0.f};
    __syncthreads();

    for (int k0 = 0; k0 < 128; k0 += 64) {
        const float* tab = k0 ? time_table : day_table;
        const int*   ids = k0 ? timel : dayl;
#pragma unroll
        for (int it = 0; it < 4; it++) {
            int c = it * 256 + t;
            int r = c >> 3, cc = (c & 7) * 8;
            const float* p = &tab[(size_t)ids[r] * 64 + cc];
            float4 v0 = *(const float4*)p;
            float4 v1 = *(const float4*)(p + 4);
            union { unsigned short u[8]; short8 v; } tm8;
            tm8.u[0] = bf16_rn(v0.x); tm8.u[1] = bf16_rn(v0.y);
            tm8.u[2] = bf16_rn(v0.z); tm8.u[3] = bf16_rn(v0.w);
            tm8.u[4] = bf16_rn(v1.x); tm8.u[5] = bf16_rn(v1.y);
            tm8.u[6] = bf16_rn(v1.z); tm8.u[7] = bf16_rn(v1.w);
            *(short8*)&Al[r][cc] = tm8.v;
        }
#pragma unroll
        for (int it = 0; it < 4; it++) {
            int c = it * 256 + t;
            int r = c >> 3, cc = (c & 7) * 8;
            *(short8*)&Bl[r][cc] = *(const short8*)&Wt[(size_t)r * 128 + k0 + cc];
        }
        __syncthreads();
#pragma unroll
        for (int ks = 0; ks < 64; ks += 32) {
            short8 af[TM], bfr[TN];
#pragma unroll
            for (int i = 0; i < TM; i++)
                af[i] = *(const short8*)&Al[wm0 + i * 16 + ln][ks + q8];
#pragma unroll
            for (int j = 0; j < TN; j++)
                bfr[j] = *(const short8*)&Bl[wn0 + j * 16 + ln][ks + q8];
#pragma unroll
            for (int i = 0; i < TM; i++)
#pragma unroll
                for (int j = 0; j < TN; j++)
                    acc[i][j] = __builtin_amdgcn_mfma_f32_16x16x32_bf16(af[i], bfr[j], acc[i][j], 0, 0, 0);
        }
        __syncthreads();
    }
    const int qr = (lane >> 4) * 4;
#pragma unroll
    for (int i = 0; i < TM; i++) {
#pragma unroll
        for (int j = 0; j < TN; j++) {
            int col = wn0 + j * 16 + ln;
            float bv = bias[col];
#pragma unroll
            for (int r = 0; r < 4; r++) {
                int row = row0 + wm0 + i * 16 + qr + r;
                float v = fmaxf(acc[i][j][r] + bv, 0.f);
                Cout[(size_t)row * 128 + col] = bf16_rn(v);
            }
        }
    }
}

// ---------------- head1: fused gather A (h[o]|h[d]|temporal|mode), K=448, N=256 -----

__global__ __launch_bounds__(256) void k_head1m(const unsigned short* __restrict__ hb,
                                                const unsigned short* __restrict__ tmp,
                                                const int* __restrict__ orig,
                                                const int* __restrict__ dest,
                                                const int* __restrict__ mode_ids,
                                                const float* __restrict__ mode_table,
                                                const unsigned short* __restrict__ Wt,
                                                const float* __restrict__ bias,
                                                unsigned short* __restrict__ z1) {
    constexpr int TM = 4, TN = 4;
    __shared__ unsigned short Al[128][72];
    __shared__ unsigned short Bl[128][72];
    __shared__ int io[128], idd[128], im[128];
    const int t = threadIdx.x;
    const int lane = t & 63, wave = t >> 6;
    const int ln = lane & 15, q8 = (lane >> 4) * 8;
    const int row0 = blockIdx.x * 128;
    const int col0 = blockIdx.y * 128;
    const int wm0 = (wave >> 1) * 64, wn0 = (wave & 1) * 64;
    if (t < 128) {
        io[t] = orig[row0 + t];
        idd[t] = dest[row0 + t];
        im[t] = mode_ids[row0 + t];
    }
    f32x4 acc[TM][TN];
#pragma unroll
    for (int i = 0; i < TM; i++)
#pragma unroll
        for (int j = 0; j < TN; j++) acc[i][j] = (f32x4){0.f, 0.f, 0.f, 0.f};
    __syncthreads();

    for (int k0 = 0; k0 < 448; k0 += 64) {
#pragma unroll
        for (int it = 0; it < 4; it++) {
            int c = it * 256 + t;
            int r = c >> 3, cc = (c & 7) * 8;
            int gk = k0 + cc;
            short8 v;
            if (gk < 128)       v = *(const short8*)&hb[(size_t)io[r] * 128 + gk];
            else if (gk < 256)  v = *(const short8*)&hb[(size_t)idd[r] * 128 + (gk - 128)];
            else if (gk < 384)  v = *(const short8*)&tmp[(size_t)(row0 + r) * 128 + (gk - 256)];
            else {
                const float* mp = &mode_table[(size_t)im[r] * 64 + (gk - 384)];
                float4 v0 = *(const float4*)mp;
                float4 v1 = *(const float4*)(mp + 4);
                union { unsigned short u[8]; short8 v; } tm8;
                tm8.u[0] = bf16_rn(v0.x); tm8.u[1] = bf16_rn(v0.y);
                tm8.u[2] = bf16_rn(v0.z); tm8.u[3] = bf16_rn(v0.w);
                tm8.u[4] = bf16_rn(v1.x); tm8.u[5] = bf16_rn(v1.y);
                tm8.u[6] = bf16_rn(v1.z); tm8.u[7] = bf16_rn(v1.w);
                v = tm8.v;
            }
            *(short8*)&Al[r][cc] = v;
        }
#pragma unroll
        for (int it = 0; it < 4; it++) {
            int c = it * 256 + t;
            int r = c >> 3, cc = (c & 7) * 8;
            *(short8*)&Bl[r][cc] = *(const short8*)&Wt[(size_t)(col0 + r) * 448 + k0 + cc];
        }
        __syncthreads();
#pragma unroll
        for (int ks = 0; ks < 64; ks += 32) {
            short8 af[TM], bfr[TN];
#pragma unroll
            for (int i = 0; i < TM; i++)
                af[i] = *(const short8*)&Al[wm0 + i * 16 + ln][ks + q8];
#pragma unroll
            for (int j = 0; j < TN; j++)
                bfr[j] = *(const short8*)&Bl[wn0 + j * 16 + ln][ks + q8];
#pragma unroll
            for (int i = 0; i < TM; i++)
#pragma unroll
                for (int j = 0; j < TN; j++)
                    acc[i][j] = __builtin_amdgcn_mfma_f32_16x16x32_bf16(af[i], bfr[j], acc[i][j], 0, 0, 0);
        }
        __syncthreads();
    }
    const int qr = (lane >> 4) * 4;
#pragma unroll
    for (int i = 0; i < TM; i++) {
#pragma unroll
        for (int j = 0; j < TN; j++) {
            int col = col0 + wn0 + j * 16 + ln;
            float bv = bias[col];
#pragma unroll
            for (int r = 0; r < 4; r++) {
                int row = row0 + wm0 + i * 16 + qr + r;
                float v = fmaxf(acc[i][j][r] + bv, 0.f);
                z1[(size_t)row * 256 + col] = bf16_rn(v);
            }
        }
    }
}

// ---------------- edge aggregation (fp8 gather): wave = 8 nodes, 8 lanes/node -------
// lane l (0..7) covers 16B (16 fp8) of the 128B row; 64 edge-gathers in flight/wave.
// epair = (src, dinv[src]); out bf16 = relu(dinv_d*(sum + dinv_d*hw[d]) + bias)

__global__ __launch_bounds__(256) void k_agg8(const unsigned char* __restrict__ hwp,
                                              const int2* __restrict__ epair,
                                              const int* __restrict__ offsets,
                                              const float* __restrict__ dinv,
                                              const float* __restrict__ bias,
                                              unsigned short* __restrict__ out) {
    const int wid = blockIdx.x * 4 + (threadIdx.x >> 6);
    const int lane = threadIdx.x & 63;
    const int g = lane >> 3, l = lane & 7;
    const int node = wid * 8 + g;
    if (node >= NN) return;
    float acc[16];
#pragma unroll
    for (int i = 0; i < 16; i++) acc[i] = 0.f;
    const int beg = offsets[node], end = offsets[node + 1];
    for (int e = beg; e < end; e += 8) {
        int2 p[8];
#pragma unroll
        for (int j = 0; j < 8; j++) {
            int ee = e + j;
            p[j] = epair[(ee < end) ? ee : (end - 1)];
        }
        uint4 v[8];
#pragma unroll
        for (int j = 0; j < 8; j++)
            v[j] = *(const uint4*)&hwp[(size_t)p[j].x * 128 + l * 16];
#pragma unroll
        for (int j = 0; j < 8; j++) {
            float c = (e + j < end) ? __builtin_bit_cast(float, p[j].y) : 0.f;
            float f[16];
            unpack4_e4m3(v[j].x, f + 0);
            unpack4_e4m3(v[j].y, f + 4);
            unpack4_e4m3(v[j].z, f + 8);
            unpack4_e4m3(v[j].w, f + 12);
#pragma unroll
            for (int i = 0; i < 16; i++) acc[i] = fmaf(f[i], c, acc[i]);
        }
    }
    float dd = dinv[node];
    uint4 sv = *(const uint4*)&hwp[(size_t)node * 128 + l * 16];
    float fs[16];
    unpack4_e4m3(sv.x, fs + 0);
    unpack4_e4m3(sv.y, fs + 4);
    unpack4_e4m3(sv.z, fs + 8);
    unpack4_e4m3(sv.w, fs + 12);
    float bb[16];
#pragma unroll
    for (int i = 0; i < 4; i++)
        *(float4*)&bb[4 * i] = *(const float4*)&bias[l * 16 + 4 * i];
    union { unsigned short u[16]; short8 v[2]; } o;
#pragma unroll
    for (int i = 0; i < 16; i++) {
        float s = fmaf(fs[i], dd, acc[i]);
        float v = fmaf(s, dd, bb[i]);
        o.u[i] = bf16_rn(fmaxf(v, 0.f));
    }
    *(short8*)&out[(size_t)node * 128 + l * 16] = o.v[0];
    *(short8*)&out[(size_t)node * 128 + l * 16 + 8] = o.v[1];
}

// ---------------- head4: [B,64] @ [64,1] + sigmoid ----------------------------------

__global__ __launch_bounds__(256) void k_head4(const float* __restrict__ z3,
                                               const float* __restrict__ Wh4,
                                               const float* __restrict__ bh4,
                                               float* __restrict__ out) {
    __shared__ float w[64];
    int t = threadIdx.x;
    if (t < 64) w[t] = Wh4[t];
    __syncthreads();
    int r = blockIdx.x * 16 + (t / 16);
    int q = t % 16;
    const float4* z4 = (const float4*)z3;
    float4 v = z4[(size_t)r * 16 + q];
    float4 wq = *(const float4*)&w[4 * q];
    float s = v.x * wq.x + v.y * wq.y + v.z * wq.z + v.w * wq.w;
#pragma unroll
    for (int off = 1; off < 16; off <<= 1) s += __shfl_xor(s, off, 64);
    if (q == 0) out[r] = 1.0f / (1.0f + expf(-(s + bh4[0])));
}

// ---------------- launch ------------------------------------------------------------

extern "C" void kernel_launch(void* const* d_in, const int* in_sizes, int n_in,
                              void* d_out, int out_size, void* d_ws, size_t ws_size,
                              hipStream_t stream) {
    const float* x          = (const float*)d_in[0];
    const int*   eidx       = (const int*)d_in[1];
    const int*   esrc       = eidx;
    const int*   edst       = eidx + EE;
    const int*   origin     = (const int*)d_in[2];
    const int*   destid     = (const int*)d_in[3];
    const int*   day_ids    = (const int*)d_in[4];
    const int*   time_ids   = (const int*)d_in[5];
    const int*   mode_ids   = (const int*)d_in[6];
    const float* W1 = (const float*)d_in[7];   const float* b1 = (const float*)d_in[8];
    const float* W2 = (const float*)d_in[9];   const float* b2 = (const float*)d_in[10];
    const float* W3 = (const float*)d_in[11];  const float* b3 = (const float*)d_in[12];
    const float* day_table  = (const float*)d_in[13];
    const float* time_table = (const float*)d_in[14];
    const float* mode_table = (const float*)d_in[15];
    const float* Wf  = (const float*)d_in[16]; const float* bf  = (const float*)d_in[17];
    const float* Wh1 = (const float*)d_in[18]; const float* bh1 = (const float*)d_in[19];
    const float* Wh2 = (const float*)d_in[20]; const float* bh2 = (const float*)d_in[21];
    const float* Wh3 = (const float*)d_in[22]; const float* bh3 = (const float*)d_in[23];
    const float* Wh4 = (const float*)d_in[24]; const float* bh4 = (const float*)d_in[25];
    float* out = (float*)d_out;

    char* wsb = (char*)d_ws;
    size_t off = 0;
    auto alloc = [&](size_t bytes) -> char* {
        char* p = wsb + off;
        off = (off + bytes + 511) & ~(size_t)511;
        return p;
    };
    int*   bcnt    = (int*)alloc((NBK + 1) * 4);
    int*   bbase   = (int*)alloc((NBK + 1) * 4);
    int*   bcur    = (int*)alloc((NBK + 1) * 4);
    int*   offsets = (int*)alloc((size_t)(NN + 1) * 4);
    float* dinv    = (float*)alloc((size_t)NN * 4);
    int2*  binned  = (int2*)alloc((size_t)EE * 8);
    int2*  epair   = (int2*)alloc((size_t)EE * 8);
    unsigned short* Wt1  = (unsigned short*)alloc(128 * 128 * 2);
    unsigned short* Wt2  = (unsigned short*)alloc(128 * 128 * 2);
    unsigned short* Wt3  = (unsigned short*)alloc(128 * 128 * 2);
    unsigned short* Wtf  = (unsigned short*)alloc(128 * 128 * 2);
    unsigned short* Wth1 = (unsigned short*)alloc(256 * 448 * 2);
    unsigned short* Wth2 = (unsigned short*)alloc(128 * 256 * 2);
    unsigned short* Wth3 = (unsigned short*)alloc(64 * 128 * 2);
    unsigned char*  bufHW = (unsigned char*)alloc((size_t)NN * 128);      // fp8 hw
    unsigned short* bufH  = (unsigned short*)alloc((size_t)NN * 128 * 2); // bf16 h
    unsigned short* temporal = (unsigned short*)alloc((size_t)BQ * 128 * 2);
    unsigned short* z1 = (unsigned short*)alloc((size_t)BQ * 256 * 2);
    float* z3 = (float*)alloc((size_t)BQ * 64 * 4);
    unsigned short* z2 = temporal;  // temporal dead after head1m

    hipMemsetAsync(bcnt, 0, (NBK + 1) * 4, stream);
    k_bcount<<<256, 256, 0, stream>>>(edst, bcnt);
    k_bscan<<<1, 512, 0, stream>>>(bcnt, bbase, bcur);
    k_bin<<<256, 256, 0, stream>>>(esrc, edst, bcur, binned);
    k_boff<<<NBK, 256, 0, stream>>>(binned, bbase, offsets, dinv);
    k_place<<<NBK, 256, 0, stream>>>(binned, bbase, offsets, dinv, epair);

    k_wtall<<<(221184 + 255) / 256, 256, 0, stream>>>(W1, W2, W3, Wf, Wh1, Wh2, Wh3,
                                                      Wt1, Wt2, Wt3, Wtf, Wth1, Wth2, Wth3);

    const int GB = (NN + 127) / 128;   // 782
    const int AB = (NN + 31) / 32;     // 3125 blocks, 32 nodes/block
    k_mfma<128, 128, 4, 0, 2, 1><<<dim3(GB, 1), 256, 0, stream>>>(x, Wt1, nullptr, bufHW, NN, 128);
    k_agg8<<<AB, 256, 0, stream>>>(bufHW, epair, offsets, dinv, b1, bufH);
    k_mfma<128, 128, 4, 0, 2, 0><<<dim3(GB, 1), 256, 0, stream>>>(bufH, Wt2, nullptr, bufHW, NN, 128);
    k_agg8<<<AB, 256, 0, stream>>>(bufHW, epair, offsets, dinv, b2, bufH);
    k_mfma<128, 128, 4, 0, 2, 0><<<dim3(GB, 1), 256, 0, stream>>>(bufH, Wt3, nullptr, bufHW, NN, 128);
    k_agg8<<<AB, 256, 0, stream>>>(bufHW, epair, offsets, dinv, b3, bufH);
    // final h = bufH (bf16)

    k_tempm<<<BQ / 128, 256, 0, stream>>>(day_ids, time_ids, day_table, time_table,
                                          Wtf, bf, temporal);
    k_head1m<<<dim3(BQ / 128, 2), 256, 0, stream>>>(bufH, temporal, origin, destid, mode_ids,
                                                    mode_table, Wth1, bh1, z1);
    k_mfma<256, 128, 4, 1, 1, 0><<<dim3(BQ / 128, 1), 256, 0, stream>>>(z1, Wth2, bh2, z2, BQ, 128);
    k_mfma<128, 64, 2, 1, 0, 0><<<dim3(BQ / 128, 1), 256, 0, stream>>>(z2, Wth3, bh3, z3, BQ, 64);
    k_head4<<<BQ / 16, 256, 0, stream>>>(z3, Wh4, bh4, out);
}

// Round 7
// 485.271 us; speedup vs baseline: 2.8854x; 1.0419x over previous
//
#include <hip/hip_runtime.h>

#define NN 100000   // nodes
#define EE 1600000  // edges
#define BQ 65536    // queries
#define NBK 391     // node buckets of 256 (ceil(NN/256))
#define ECH 6250    // edges per binning block (EE/256)

typedef __attribute__((ext_vector_type(8))) short short8;
typedef __attribute__((ext_vector_type(4))) float f32x4;
typedef __attribute__((ext_vector_type(2))) float f32x2;

__device__ __forceinline__ unsigned short bf16_rn(float f) {
    unsigned u = __builtin_bit_cast(unsigned, f);
    u += 0x7fff + ((u >> 16) & 1);
    return (unsigned short)(u >> 16);
}

// ---------------- fp8 e4m3 helpers (HW cvt with SW fallback) ------------------------

#if defined(__has_builtin)
#if __has_builtin(__builtin_amdgcn_cvt_pk_fp8_f32) && __has_builtin(__builtin_amdgcn_cvt_pk_f32_fp8)
#define HW_FP8 1
#endif
#endif
#ifndef HW_FP8
#define HW_FP8 0
#endif

__device__ __forceinline__ unsigned char sw_f32_to_e4m3(float f) {
    float a = fabsf(f);
    unsigned s = __builtin_bit_cast(unsigned, f) >> 31;
    if (!(a < 448.f)) return (unsigned char)((s << 7) | 0x7E);
    if (a < 0.015625f) {
        int q = (int)rintf(a * 512.0f);
        return (unsigned char)((s << 7) | q);
    }
    int e; float m = frexpf(a, &e);
    int q = (int)rintf(m * 16.0f);
    int exp = e - 1 + 7;
    if (q == 16) { q = 8; exp++; }
    if (exp >= 16 || (exp == 15 && q == 15)) return (unsigned char)((s << 7) | 0x7E);
    return (unsigned char)((s << 7) | (exp << 3) | (q - 8));
}
__device__ __forceinline__ float sw_e4m3_to_f32(unsigned char v) {
    unsigned s = v >> 7, e = (v >> 3) & 15, m = v & 7;
    float r = e ? ldexpf((float)(8 + m), (int)e - 10) : ldexpf((float)m, -9);
    return s ? -r : r;
}

__device__ __forceinline__ unsigned char f32_to_e4m3b(float f) {
#if HW_FP8
    return (unsigned char)(__builtin_amdgcn_cvt_pk_fp8_f32(f, f, 0, false) & 0xFF);
#else
    return sw_f32_to_e4m3(f);
#endif
}
__device__ __forceinline__ void unpack4_e4m3(unsigned v, float* o) {
#if HW_FP8
    f32x2 lo = __builtin_amdgcn_cvt_pk_f32_fp8((int)v, false);
    f32x2 hi = __builtin_amdgcn_cvt_pk_f32_fp8((int)v, true);
    o[0] = lo[0]; o[1] = lo[1]; o[2] = hi[0]; o[3] = hi[1];
#else
    o[0] = sw_e4m3_to_f32(v & 0xFF);
    o[1] = sw_e4m3_to_f32((v >> 8) & 0xFF);
    o[2] = sw_e4m3_to_f32((v >> 16) & 0xFF);
    o[3] = sw_e4m3_to_f32((v >> 24) & 0xFF);
#endif
}

// ---------------- bucket count / scan / bin / offsets / place -----------------------

__global__ __launch_bounds__(256) void k_bcount(const int* __restrict__ dst,
                                                int* __restrict__ bcnt) {
    __shared__ int h[NBK];
    int t = threadIdx.x, b = blockIdx.x;
    for (int j = t; j < NBK; j += 256) h[j] = 0;
    __syncthreads();
    int lo = b * ECH, hi = lo + ECH;
    for (int i = lo + t; i < hi; i += 256) atomicAdd(&h[dst[i] >> 8], 1);
    __syncthreads();
    for (int j = t; j < NBK; j += 256)
        if (h[j]) atomicAdd(&bcnt[j], h[j]);
}

__global__ __launch_bounds__(512) void k_bscan(const int* __restrict__ bcnt,
                                               int* __restrict__ bbase,
                                               int* __restrict__ bcur) {
    __shared__ int sd[512];
    int t = threadIdx.x;
    int v = (t < NBK) ? bcnt[t] : 0;
    sd[t] = v;
    __syncthreads();
    for (int o = 1; o < 512; o <<= 1) {
        int x = (t >= o) ? sd[t - o] : 0;
        __syncthreads();
        sd[t] += x;
        __syncthreads();
    }
    if (t < NBK) { int e = sd[t] - v; bbase[t] = e; bcur[t] = e; }
    if (t == 0) bbase[NBK] = EE;
}

__global__ __launch_bounds__(256) void k_bin(const int* __restrict__ src,
                                             const int* __restrict__ dst,
                                             int* __restrict__ bcur,
                                             int2* __restrict__ binned) {
    __shared__ int h[NBK];
    __shared__ int cur[NBK];
    int t = threadIdx.x, b = blockIdx.x;
    for (int j = t; j < NBK; j += 256) { h[j] = 0; cur[j] = 0; }
    __syncthreads();
    int lo = b * ECH, hi = lo + ECH;
    for (int i = lo + t; i < hi; i += 256) atomicAdd(&h[dst[i] >> 8], 1);
    __syncthreads();
    for (int j = t; j < NBK; j += 256)
        if (h[j]) h[j] = atomicAdd(&bcur[j], h[j]);
    __syncthreads();
    for (int i = lo + t; i < hi; i += 256) {
        int d = dst[i], bk = d >> 8;
        int pos = h[bk] + atomicAdd(&cur[bk], 1);
        binned[pos] = make_int2(src[i], d);
    }
}

__global__ __launch_bounds__(256) void k_boff(const int2* __restrict__ binned,
                                              const int* __restrict__ bbase,
                                              int* __restrict__ offsets,
                                              float* __restrict__ dinv) {
    __shared__ int lh[256];
    __shared__ int sd[256];
    int t = threadIdx.x, b = blockIdx.x;
    lh[t] = 0;
    __syncthreads();
    int lo = bbase[b], hi = bbase[b + 1];
    for (int i = lo + t; i < hi; i += 256) atomicAdd(&lh[binned[i].y & 255], 1);
    __syncthreads();
    int v = lh[t];
    sd[t] = v;
    __syncthreads();
    for (int o = 1; o < 256; o <<= 1) {
        int x = (t >= o) ? sd[t - o] : 0;
        __syncthreads();
        sd[t] += x;
        __syncthreads();
    }
    int node = (b << 8) + t;
    if (node < NN) {
        offsets[node] = lo + (sd[t] - v);
        dinv[node] = rsqrtf((float)v + 1.0f);
    }
    if (b == NBK - 1 && t == 0) offsets[NN] = EE;
}

__global__ __launch_bounds__(256) void k_place(const int2* __restrict__ binned,
                                               const int* __restrict__ bbase,
                                               const int* __restrict__ offsets,
                                               const float* __restrict__ dinv,
                                               int2* __restrict__ epair) {
    __shared__ int lcur[256];
    int t = threadIdx.x, b = blockIdx.x;
    int node = (b << 8) + t;
    lcur[t] = (node < NN) ? offsets[node] : 0;
    __syncthreads();
    int lo = bbase[b], hi = bbase[b + 1];
    for (int i = lo + t; i < hi; i += 256) {
        int2 e = binned[i];
        int pos = atomicAdd(&lcur[e.y & 255], 1);
        epair[pos] = make_int2(e.x, __builtin_bit_cast(int, dinv[e.x]));
    }
}

// ---------------- fused weight convert -> bf16 transposed ---------------------------
// Wh1 only needs its first 256 rows (route part); temporal/mode folded into CC.

__global__ __launch_bounds__(256) void k_wtall(const float* __restrict__ W1,
                                               const float* __restrict__ W2,
                                               const float* __restrict__ W3,
                                               const float* __restrict__ Wf,
                                               const float* __restrict__ Wh1,
                                               const float* __restrict__ Wh2,
                                               const float* __restrict__ Wh3,
                                               unsigned short* __restrict__ Wt1,
                                               unsigned short* __restrict__ Wt2,
                                               unsigned short* __restrict__ Wt3,
                                               unsigned short* __restrict__ Wtf,
                                               unsigned short* __restrict__ Wth1,
                                               unsigned short* __restrict__ Wth2,
                                               unsigned short* __restrict__ Wth3) {
    int i = blockIdx.x * 256 + threadIdx.x;
    const float* W; unsigned short* Wt; int K, N, idx;
    if (i < 16384)       { W = W1;  Wt = Wt1;  K = 128; N = 128; idx = i; }
    else if (i < 32768)  { W = W2;  Wt = Wt2;  K = 128; N = 128; idx = i - 16384; }
    else if (i < 49152)  { W = W3;  Wt = Wt3;  K = 128; N = 128; idx = i - 32768; }
    else if (i < 65536)  { W = Wf;  Wt = Wtf;  K = 128; N = 128; idx = i - 49152; }
    else if (i < 131072) { W = Wh1; Wt = Wth1; K = 256; N = 256; idx = i - 65536; }
    else if (i < 163840) { W = Wh2; Wt = Wth2; K = 256; N = 128; idx = i - 131072; }
    else if (i < 172032) { W = Wh3; Wt = Wth3; K = 128; N = 64;  idx = i - 163840; }
    else return;
    int k = idx / N, n = idx % N;
    Wt[(size_t)n * K + k] = bf16_rn(W[idx]);
}

// ---------------- CC table: combined temporal+mode+bias contribution ----------------
// CC[(day*5+time)*3+mode][n] = bh1[n] + temporal·Wh1[256:384][n] + mode_emb·Wh1[384:448][n]
// where temporal = relu([day_emb;time_emb]·Wf + bf). 30 combos, full fp32.

__global__ __launch_bounds__(256) void k_cc(const float* __restrict__ day_table,
                                            const float* __restrict__ time_table,
                                            const float* __restrict__ mode_table,
                                            const float* __restrict__ Wf,
                                            const float* __restrict__ bf,
                                            const float* __restrict__ Wh1,
                                            const float* __restrict__ bh1,
                                            float* __restrict__ CC) {
    int c = blockIdx.x;                   // 0..29
    int mode = c % 3, dt = c / 3, time = dt % 5, day = dt / 5;
    __shared__ float temp[128];
    int t = threadIdx.x;
    if (t < 128) {
        float s = bf[t];
        for (int j = 0; j < 64; j++) s = fmaf(day_table[day * 64 + j],  Wf[j * 128 + t], s);
        for (int j = 0; j < 64; j++) s = fmaf(time_table[time * 64 + j], Wf[(64 + j) * 128 + t], s);
        temp[t] = fmaxf(s, 0.f);
    }
    __syncthreads();
    float s = bh1[t];
    for (int k = 0; k < 128; k++) s = fmaf(temp[k], Wh1[(size_t)(256 + k) * 256 + t], s);
    for (int j = 0; j < 64; j++)  s = fmaf(mode_table[mode * 64 + j], Wh1[(size_t)(384 + j) * 256 + t], s);
    CC[c * 256 + t] = s;
}

// ---------------- bf16 MFMA GEMM: C = A @ Wt^T (+bias)(+relu) -----------------------
// OUTM: 0=f32, 1=bf16, 2=fp8-e4m3

template <int K, int BN, int TN, int ACT, int OUTM, int AF32>
__global__ __launch_bounds__(256) void k_mfma(const void* __restrict__ Ap,
                                              const unsigned short* __restrict__ Wt,
                                              const float* __restrict__ bias,
                                              void* __restrict__ Cp,
                                              int M, int Ntot) {
    constexpr int TM = 4;
    __shared__ unsigned short Al[128][72];
    __shared__ unsigned short Bl[BN][72];
    const int t = threadIdx.x;
    const int lane = t & 63, wave = t >> 6;
    const int ln = lane & 15, q8 = (lane >> 4) * 8;
    const int row0 = blockIdx.x * 128;
    const int col0 = blockIdx.y * BN;
    const int wm0 = (wave >> 1) * 64;
    const int wn0 = (wave & 1) * (TN * 16);
    f32x4 acc[TM][TN];
#pragma unroll
    for (int i = 0; i < TM; i++)
#pragma unroll
        for (int j = 0; j < TN; j++) acc[i][j] = (f32x4){0.f, 0.f, 0.f, 0.f};

    for (int k0 = 0; k0 < K; k0 += 64) {
#pragma unroll
        for (int it = 0; it < 4; it++) {
            int c = it * 256 + t;
            int r = c >> 3, cc = (c & 7) * 8;
            int grow = row0 + r;
            if (AF32) {
                const float* A = (const float*)Ap;
                union { unsigned short u[8]; short8 v; } tm8;
                if (grow < M) {
                    float4 v0 = *(const float4*)&A[(size_t)grow * K + k0 + cc];
                    float4 v1 = *(const float4*)&A[(size_t)grow * K + k0 + cc + 4];
                    tm8.u[0] = bf16_rn(v0.x); tm8.u[1] = bf16_rn(v0.y);
                    tm8.u[2] = bf16_rn(v0.z); tm8.u[3] = bf16_rn(v0.w);
                    tm8.u[4] = bf16_rn(v1.x); tm8.u[5] = bf16_rn(v1.y);
                    tm8.u[6] = bf16_rn(v1.z); tm8.u[7] = bf16_rn(v1.w);
                } else {
                    tm8.v = (short8){0, 0, 0, 0, 0, 0, 0, 0};
                }
                *(short8*)&Al[r][cc] = tm8.v;
            } else {
                const unsigned short* A = (const unsigned short*)Ap;
                short8 v = (short8){0, 0, 0, 0, 0, 0, 0, 0};
                if (grow < M) v = *(const short8*)&A[(size_t)grow * K + k0 + cc];
                *(short8*)&Al[r][cc] = v;
            }
        }
#pragma unroll
        for (int it = 0; it < BN / 32; it++) {
            int c = it * 256 + t;
            int r = c >> 3, cc = (c & 7) * 8;
            *(short8*)&Bl[r][cc] = *(const short8*)&Wt[(size_t)(col0 + r) * K + k0 + cc];
        }
        __syncthreads();
#pragma unroll
        for (int ks = 0; ks < 64; ks += 32) {
            short8 af[TM], bfr[TN];
#pragma unroll
            for (int i = 0; i < TM; i++)
                af[i] = *(const short8*)&Al[wm0 + i * 16 + ln][ks + q8];
#pragma unroll
            for (int j = 0; j < TN; j++)
                bfr[j] = *(const short8*)&Bl[wn0 + j * 16 + ln][ks + q8];
#pragma unroll
            for (int i = 0; i < TM; i++)
#pragma unroll
                for (int j = 0; j < TN; j++)
                    acc[i][j] = __builtin_amdgcn_mfma_f32_16x16x32_bf16(af[i], bfr[j], acc[i][j], 0, 0, 0);
        }
        __syncthreads();
    }
    const int qr = (lane >> 4) * 4;
#pragma unroll
    for (int i = 0; i < TM; i++) {
#pragma unroll
        for (int j = 0; j < TN; j++) {
            int col = col0 + wn0 + j * 16 + ln;
            float bv = bias ? bias[col] : 0.f;
#pragma unroll
            for (int r = 0; r < 4; r++) {
                int row = row0 + wm0 + i * 16 + qr + r;
                if (row < M) {
                    float v = acc[i][j][r] + bv;
                    if (ACT) v = fmaxf(v, 0.f);
                    if (OUTM == 1)      ((unsigned short*)Cp)[(size_t)row * Ntot + col] = bf16_rn(v);
                    else if (OUTM == 2) ((unsigned char*)Cp)[(size_t)row * Ntot + col] = f32_to_e4m3b(v);
                    else                ((float*)Cp)[(size_t)row * Ntot + col] = v;
                }
            }
        }
    }
}

// ---------------- head1: A = [h_o | h_d], K=256, +CC[combo] epilogue ----------------

__global__ __launch_bounds__(256) void k_head1m(const unsigned short* __restrict__ hb,
                                                const int* __restrict__ orig,
                                                const int* __restrict__ dest,
                                                const int* __restrict__ day_ids,
                                                const int* __restrict__ time_ids,
                                                const int* __restrict__ mode_ids,
                                                const float* __restrict__ CC,
                                                const unsigned short* __restrict__ Wt,
                                                unsigned short* __restrict__ z1) {
    constexpr int TM = 4, TN = 4;
    __shared__ unsigned short Al[128][72];
    __shared__ unsigned short Bl[128][72];
    __shared__ int io[128], idd[128], cid[128];
    const int t = threadIdx.x;
    const int lane = t & 63, wave = t >> 6;
    const int ln = lane & 15, q8 = (lane >> 4) * 8;
    const int row0 = blockIdx.x * 128;
    const int col0 = blockIdx.y * 128;
    const int wm0 = (wave >> 1) * 64, wn0 = (wave & 1) * 64;
    if (t < 128) {
        io[t] = orig[row0 + t];
        idd[t] = dest[row0 + t];
        cid[t] = (day_ids[row0 + t] * 5 + time_ids[row0 + t]) * 3 + mode_ids[row0 + t];
    }
    f32x4 acc[TM][TN];
#pragma unroll
    for (int i = 0; i < TM; i++)
#pragma unroll
        for (int j = 0; j < TN; j++) acc[i][j] = (f32x4){0.f, 0.f, 0.f, 0.f};
    __syncthreads();

    for (int k0 = 0; k0 < 256; k0 += 64) {
#pragma unroll
        for (int it = 0; it < 4; it++) {
            int c = it * 256 + t;
            int r = c >> 3, cc = (c & 7) * 8;
            int gk = k0 + cc;
            short8 v;
            if (gk < 128) v = *(const short8*)&hb[(size_t)io[r] * 128 + gk];
            else          v = *(const short8*)&hb[(size_t)idd[r] * 128 + (gk - 128)];
            *(short8*)&Al[r][cc] = v;
        }
#pragma unroll
        for (int it = 0; it < 4; it++) {
            int c = it * 256 + t;
            int r = c >> 3, cc = (c & 7) * 8;
            *(short8*)&Bl[r][cc] = *(const short8*)&Wt[(size_t)(col0 + r) * 256 + k0 + cc];
        }
        __syncthreads();
#pragma unroll
        for (int ks = 0; ks < 64; ks += 32) {
            short8 af[TM], bfr[TN];
#pragma unroll
            for (int i = 0; i < TM; i++)
                af[i] = *(const short8*)&Al[wm0 + i * 16 + ln][ks + q8];
#pragma unroll
            for (int j = 0; j < TN; j++)
                bfr[j] = *(const short8*)&Bl[wn0 + j * 16 + ln][ks + q8];
#pragma unroll
            for (int i = 0; i < TM; i++)
#pragma unroll
                for (int j = 0; j < TN; j++)
                    acc[i][j] = __builtin_amdgcn_mfma_f32_16x16x32_bf16(af[i], bfr[j], acc[i][j], 0, 0, 0);
        }
        __syncthreads();
    }
    const int qr = (lane >> 4) * 4;
#pragma unroll
    for (int i = 0; i < TM; i++) {
#pragma unroll
        for (int j = 0; j < TN; j++) {
            int col = col0 + wn0 + j * 16 + ln;
#pragma unroll
            for (int r = 0; r < 4; r++) {
                int rl = wm0 + i * 16 + qr + r;
                float v = acc[i][j][r] + CC[cid[rl] * 256 + col];
                z1[(size_t)(row0 + rl) * 256 + col] = bf16_rn(fmaxf(v, 0.f));
            }
        }
    }
}

// ---------------- edge aggregation (fp8 gather): wave = 8 nodes, 8 lanes/node -------

__global__ __launch_bounds__(256) void k_agg8(const unsigned char* __restrict__ hwp,
                                              const int2* __restrict__ epair,
                                              const int* __restrict__ offsets,
                                              const float* __restrict__ dinv,
                                              const float* __restrict__ bias,
                                              unsigned short* __restrict__ out) {
    const int wid = blockIdx.x * 4 + (threadIdx.x >> 6);
    const int lane = threadIdx.x & 63;
    const int g = lane >> 3, l = lane & 7;
    const int node = wid * 8 + g;
    if (node >= NN) return;
    float acc[16];
#pragma unroll
    for (int i = 0; i < 16; i++) acc[i] = 0.f;
    const int beg = offsets[node], end = offsets[node + 1];
    for (int e = beg; e < end; e += 8) {
        int2 p[8];
#pragma unroll
        for (int j = 0; j < 8; j++) {
            int ee = e + j;
            p[j] = epair[(ee < end) ? ee : (end - 1)];
        }
        uint4 v[8];
#pragma unroll
        for (int j = 0; j < 8; j++)
            v[j] = *(const uint4*)&hwp[(size_t)p[j].x * 128 + l * 16];
#pragma unroll
        for (int j = 0; j < 8; j++) {
            float c = (e + j < end) ? __builtin_bit_cast(float, p[j].y) : 0.f;
            float f[16];
            unpack4_e4m3(v[j].x, f + 0);
            unpack4_e4m3(v[j].y, f + 4);
            unpack4_e4m3(v[j].z, f + 8);
            unpack4_e4m3(v[j].w, f + 12);
#pragma unroll
            for (int i = 0; i < 16; i++) acc[i] = fmaf(f[i], c, acc[i]);
        }
    }
    float dd = dinv[node];
    uint4 sv = *(const uint4*)&hwp[(size_t)node * 128 + l * 16];
    float fs[16];
    unpack4_e4m3(sv.x, fs + 0);
    unpack4_e4m3(sv.y, fs + 4);
    unpack4_e4m3(sv.z, fs + 8);
    unpack4_e4m3(sv.w, fs + 12);
    float bb[16];
#pragma unroll
    for (int i = 0; i < 4; i++)
        *(float4*)&bb[4 * i] = *(const float4*)&bias[l * 16 + 4 * i];
    union { unsigned short u[16]; short8 v[2]; } o;
#pragma unroll
    for (int i = 0; i < 16; i++) {
        float s = fmaf(fs[i], dd, acc[i]);
        float v = fmaf(s, dd, bb[i]);
        o.u[i] = bf16_rn(fmaxf(v, 0.f));
    }
    *(short8*)&out[(size_t)node * 128 + l * 16] = o.v[0];
    *(short8*)&out[(size_t)node * 128 + l * 16 + 8] = o.v[1];
}

// ---------------- fused head3+head4: out = sigmoid(relu(z2·Wh3+b3)·Wh4+b4) ----------
// block = 4 waves x 64 rows; wave: TM=4 (64 rows) x TN=4 (64 cols); K=128.
// A-frags straight from global z2; Wt3 (64x128 bf16) via L1.

__global__ __launch_bounds__(256) void k_head34(const unsigned short* __restrict__ z2,
                                                const unsigned short* __restrict__ Wt3,
                                                const float* __restrict__ bh3,
                                                const float* __restrict__ Wh4,
                                                const float* __restrict__ bh4,
                                                float* __restrict__ out) {
    const int t = threadIdx.x;
    const int lane = t & 63, wave = t >> 6;
    const int ln = lane & 15, q8 = (lane >> 4) * 8;
    const int rowbase = blockIdx.x * 256 + wave * 64;
    f32x4 acc[4][4];
#pragma unroll
    for (int i = 0; i < 4; i++)
#pragma unroll
        for (int j = 0; j < 4; j++) acc[i][j] = (f32x4){0.f, 0.f, 0.f, 0.f};
#pragma unroll
    for (int ks = 0; ks < 128; ks += 32) {
        short8 af[4], bfr[4];
#pragma unroll
        for (int i = 0; i < 4; i++)
            af[i] = *(const short8*)&z2[(size_t)(rowbase + i * 16 + ln) * 128 + ks + q8];
#pragma unroll
        for (int j = 0; j < 4; j++)
            bfr[j] = *(const short8*)&Wt3[(size_t)(j * 16 + ln) * 128 + ks + q8];
#pragma unroll
        for (int i = 0; i < 4; i++)
#pragma unroll
            for (int j = 0; j < 4; j++)
                acc[i][j] = __builtin_amdgcn_mfma_f32_16x16x32_bf16(af[i], bfr[j], acc[i][j], 0, 0, 0);
    }
    const int qr = (lane >> 4) * 4;
    float b3c[4], w4c[4];
#pragma unroll
    for (int j = 0; j < 4; j++) {
        b3c[j] = bh3[j * 16 + ln];
        w4c[j] = Wh4[j * 16 + ln];
    }
    float b4 = bh4[0];
    float part[4][4];
#pragma unroll
    for (int i = 0; i < 4; i++)
#pragma unroll
        for (int r = 0; r < 4; r++) {
            float s = 0.f;
#pragma unroll
            for (int j = 0; j < 4; j++)
                s = fmaf(fmaxf(acc[i][j][r] + b3c[j], 0.f), w4c[j], s);
            part[i][r] = s;
        }
#pragma unroll
    for (int i = 0; i < 4; i++)
#pragma unroll
        for (int r = 0; r < 4; r++) {
            float s = part[i][r];
            s += __shfl_xor(s, 1); s += __shfl_xor(s, 2);
            s += __shfl_xor(s, 4); s += __shfl_xor(s, 8);
            part[i][r] = s;
        }
    if (ln == 0) {
#pragma unroll
        for (int i = 0; i < 4; i++)
#pragma unroll
            for (int r = 0; r < 4; r++)
                out[rowbase + i * 16 + qr + r] =
                    1.0f / (1.0f + expf(-(part[i][r] + b4)));
    }
}

// ---------------- launch ------------------------------------------------------------

extern "C" void kernel_launch(void* const* d_in, const int* in_sizes, int n_in,
                              void* d_out, int out_size, void* d_ws, size_t ws_size,
                              hipStream_t stream) {
    const float* x          = (const float*)d_in[0];
    const int*   eidx       = (const int*)d_in[1];
    const int*   esrc       = eidx;
    const int*   edst       = eidx + EE;
    const int*   origin     = (const int*)d_in[2];
    const int*   destid     = (const int*)d_in[3];
    const int*   day_ids    = (const int*)d_in[4];
    const int*   time_ids   = (const int*)d_in[5];
    const int*   mode_ids   = (const int*)d_in[6];
    const float* W1 = (const float*)d_in[7];   const float* b1 = (const float*)d_in[8];
    const float* W2 = (const float*)d_in[9];   const float* b2 = (const float*)d_in[10];
    const float* W3 = (const float*)d_in[11];  const float* b3 = (const float*)d_in[12];
    const float* day_table  = (const float*)d_in[13];
    const float* time_table = (const float*)d_in[14];
    const float* mode_table = (const float*)d_in[15];
    const float* Wf  = (const float*)d_in[16]; const float* bf  = (const float*)d_in[17];
    const float* Wh1 = (const float*)d_in[18]; const float* bh1 = (const float*)d_in[19];
    const float* Wh2 = (const float*)d_in[20]; const float* bh2 = (const float*)d_in[21];
    const float* Wh3 = (const float*)d_in[22]; const float* bh3 = (const float*)d_in[23];
    const float* Wh4 = (const float*)d_in[24]; const float* bh4 = (const float*)d_in[25];
    float* out = (float*)d_out;

    char* wsb = (char*)d_ws;
    size_t off = 0;
    auto alloc = [&](size_t bytes) -> char* {
        char* p = wsb + off;
        off = (off + bytes + 511) & ~(size_t)511;
        return p;
    };
    int*   bcnt    = (int*)alloc((NBK + 1) * 4);
    int*   bbase   = (int*)alloc((NBK + 1) * 4);
    int*   bcur    = (int*)alloc((NBK + 1) * 4);
    int*   offsets = (int*)alloc((size_t)(NN + 1) * 4);
    float* dinv    = (float*)alloc((size_t)NN * 4);
    int2*  binned  = (int2*)alloc((size_t)EE * 8);
    int2*  epair   = (int2*)alloc((size_t)EE * 8);
    unsigned short* Wt1  = (unsigned short*)alloc(128 * 128 * 2);
    unsigned short* Wt2  = (unsigned short*)alloc(128 * 128 * 2);
    unsigned short* Wt3  = (unsigned short*)alloc(128 * 128 * 2);
    unsigned short* Wtf  = (unsigned short*)alloc(128 * 128 * 2);
    unsigned short* Wth1 = (unsigned short*)alloc(256 * 256 * 2);
    unsigned short* Wth2 = (unsigned short*)alloc(128 * 256 * 2);
    unsigned short* Wth3 = (unsigned short*)alloc(64 * 128 * 2);
    float* CC = (float*)alloc(30 * 256 * 4);
    unsigned char*  bufHW = (unsigned char*)alloc((size_t)NN * 128);      // fp8 hw
    unsigned short* bufH  = (unsigned short*)alloc((size_t)NN * 128 * 2); // bf16 h
    unsigned short* z1 = (unsigned short*)alloc((size_t)BQ * 256 * 2);
    unsigned short* z2 = (unsigned short*)alloc((size_t)BQ * 128 * 2);

    hipMemsetAsync(bcnt, 0, (NBK + 1) * 4, stream);
    k_bcount<<<256, 256, 0, stream>>>(edst, bcnt);
    k_bscan<<<1, 512, 0, stream>>>(bcnt, bbase, bcur);
    k_bin<<<256, 256, 0, stream>>>(esrc, edst, bcur, binned);
    k_boff<<<NBK, 256, 0, stream>>>(binned, bbase, offsets, dinv);
    k_place<<<NBK, 256, 0, stream>>>(binned, bbase, offsets, dinv, epair);

    k_wtall<<<(172032 + 255) / 256, 256, 0, stream>>>(W1, W2, W3, Wf, Wh1, Wh2, Wh3,
                                                      Wt1, Wt2, Wt3, Wtf, Wth1, Wth2, Wth3);
    k_cc<<<30, 256, 0, stream>>>(day_table, time_table, mode_table, Wf, bf, Wh1, bh1, CC);

    const int GB = (NN + 127) / 128;   // 782
    const int AB = (NN + 31) / 32;     // 3125 blocks, 32 nodes/block
    k_mfma<128, 128, 4, 0, 2, 1><<<dim3(GB, 1), 256, 0, stream>>>(x, Wt1, nullptr, bufHW, NN, 128);
    k_agg8<<<AB, 256, 0, stream>>>(bufHW, epair, offsets, dinv, b1, bufH);
    k_mfma<128, 128, 4, 0, 2, 0><<<dim3(GB, 1), 256, 0, stream>>>(bufH, Wt2, nullptr, bufHW, NN, 128);
    k_agg8<<<AB, 256, 0, stream>>>(bufHW, epair, offsets, dinv, b2, bufH);
    k_mfma<128, 128, 4, 0, 2, 0><<<dim3(GB, 1), 256, 0, stream>>>(bufH, Wt3, nullptr, bufHW, NN, 128);
    k_agg8<<<AB, 256, 0, stream>>>(bufHW, epair, offsets, dinv, b3, bufH);
    // final h = bufH (bf16)

    k_head1m<<<dim3(BQ / 128, 2), 256, 0, stream>>>(bufH, origin, destid, day_ids, time_ids,
                                                    mode_ids, CC, Wth1, z1);
    k_mfma<256, 128, 4, 1, 1, 0><<<dim3(BQ / 128, 1), 256, 0, stream>>>(z1, Wth2, bh2, z2, BQ, 128);
    k_head34<<<BQ / 256, 256, 0, stream>>>(z2, Wth3, bh3, Wh4, bh4, out);
}